// Round 2
// baseline (1283.500 us; speedup 1.0000x reference)
//
#include <hip/hip_runtime.h>
#include <hip/hip_bf16.h>

typedef __hip_bfloat16 bf16;

#define BB 4
#define LL 1024
#define DM 512
#define DS 16
#define DI 1024
#define ROWS (BB*LL)   // 4096

__device__ __forceinline__ float b2f(bf16 v) { return __bfloat162float(v); }

// ---------------------------------------------------------------------------
// Dtype detector: probe W_dt (scale 0.02, |v| <= ~0.15 if bf16).
// If data is bf16: no 16-bit word has exponent >= 127  -> bad == 0.
// If data is fp32: even words are mantissa fragments (random) -> ~50% bad.
// flag: 1 = bf16 inputs, 0 = fp32 inputs.
// ---------------------------------------------------------------------------
__global__ __launch_bounds__(256)
void detect_dtype(const unsigned short* __restrict__ p, int* __restrict__ flag)
{
    __shared__ int bad;
    if (threadIdx.x == 0) bad = 0;
    __syncthreads();
    int cnt = 0;
    #pragma unroll
    for (int r = 0; r < 16; ++r) {
        unsigned short u = p[threadIdx.x * 16 + r];
        int expo = (u >> 7) & 0xFF;
        if (expo >= 127) cnt++;               // |v| >= 1.0, inf, or nan
    }
    atomicAdd(&bad, cnt);
    __syncthreads();
    if (threadIdx.x == 0) *flag = (bad > 100) ? 0 : 1;
}

// Canonicalize any input to fp32 according to the flag.
__global__ __launch_bounds__(256)
void cvt_kernel(const void* __restrict__ src, float* __restrict__ dst, int n,
                const int* __restrict__ flag)
{
    int i = blockIdx.x * 256 + threadIdx.x;
    if (i >= n) return;
    if (*flag) dst[i] = b2f(((const bf16*)src)[i]);
    else       dst[i] = ((const float*)src)[i];
}

// ---------------------------------------------------------------------------
// Tiled GEMM: C[M,N] = A[M,K] * B[K,N] (+bias), all fp32.
// 64x64 tile, 256 threads, 4x4 micro-tile.
// ---------------------------------------------------------------------------
__global__ __launch_bounds__(256)
void gemm_tiled(const float* __restrict__ A, const float* __restrict__ Bw,
                const float* __restrict__ bias, float* __restrict__ C,
                int M, int N, int K, int clipA)
{
    __shared__ float As[16][68];
    __shared__ float Bs[16][68];

    const int tid = threadIdx.x;
    const int m0 = blockIdx.y * 64;
    const int n0 = blockIdx.x * 64;
    const int tx = tid & 15;
    const int ty = tid >> 4;

    float acc[4][4] = {};

    for (int k0 = 0; k0 < K; k0 += 16) {
        #pragma unroll
        for (int r = 0; r < 4; ++r) {
            int e = tid + r * 256;
            int m = e >> 4, k = e & 15;
            int gm = m0 + m, gk = k0 + k;
            float v = 0.f;
            if (gm < M && gk < K) v = A[(size_t)gm * K + gk];
            if (clipA) v = fminf(fmaxf(v, -10.f), 10.f);
            As[k][m] = v;
        }
        #pragma unroll
        for (int r = 0; r < 4; ++r) {
            int e = tid + r * 256;
            int k = e >> 6, n = e & 63;
            int gk = k0 + k, gn = n0 + n;
            float v = 0.f;
            if (gk < K && gn < N) v = Bw[(size_t)gk * N + gn];
            Bs[k][n] = v;
        }
        __syncthreads();

        #pragma unroll
        for (int kk = 0; kk < 16; ++kk) {
            float4 av = *(const float4*)&As[kk][ty * 4];
            float4 bv = *(const float4*)&Bs[kk][tx * 4];
            float a[4] = {av.x, av.y, av.z, av.w};
            float b[4] = {bv.x, bv.y, bv.z, bv.w};
            #pragma unroll
            for (int i = 0; i < 4; ++i)
                #pragma unroll
                for (int j = 0; j < 4; ++j)
                    acc[i][j] = fmaf(a[i], b[j], acc[i][j]);
        }
        __syncthreads();
    }

    #pragma unroll
    for (int i = 0; i < 4; ++i) {
        int gm = m0 + ty * 4 + i;
        if (gm >= M) continue;
        #pragma unroll
        for (int j = 0; j < 4; ++j) {
            int gn = n0 + tx * 4 + j;
            if (gn >= N) continue;
            float v = acc[i][j];
            if (bias) v += bias[gn];
            C[(size_t)gm * N + gn] = v;
        }
    }
}

// ---------------------------------------------------------------------------
// Depthwise causal conv (width 4) + SiLU. xp = first DI cols of xr rows.
// ---------------------------------------------------------------------------
__global__ __launch_bounds__(256)
void conv_silu(const float* __restrict__ xr, const float* __restrict__ cw,
               const float* __restrict__ cb, float* __restrict__ xc)
{
    int idx = blockIdx.x * 256 + threadIdx.x;     // ROWS*DI
    int i = idx & (DI - 1);
    int row = idx >> 10;
    int t = row & (LL - 1);

    float w0 = cw[i * 4 + 0];
    float w1 = cw[i * 4 + 1];
    float w2 = cw[i * 4 + 2];
    float w3 = cw[i * 4 + 3];

    float acc = cb[i];
    const float* base = xr + (size_t)row * 2048 + i;
    if (t >= 3) acc = fmaf(base[-3 * 2048], w0, acc);
    if (t >= 2) acc = fmaf(base[-2 * 2048], w1, acc);
    if (t >= 1) acc = fmaf(base[-1 * 2048], w2, acc);
    acc = fmaf(base[0], w3, acc);

    xc[idx] = acc / (1.f + __expf(-acc));
}

// ---------------------------------------------------------------------------
// Selective scan over t; one lane per (b,i) channel, 16 states in registers.
// Applies D-skip and silu(res) gating; writes gated y in place over xc.
// ---------------------------------------------------------------------------
__global__ __launch_bounds__(64)
void scan_kernel(float* __restrict__ xcy, const float* __restrict__ delta,
                 const float* __restrict__ ssm, const float* __restrict__ xr,
                 const float* __restrict__ A_log, const float* __restrict__ Dskip)
{
    const int b = blockIdx.y;
    const int i = blockIdx.x * 64 + threadIdx.x;

    float a[DS];
    #pragma unroll
    for (int s = 0; s < DS; ++s) a[s] = A_log[s];
    const float dsk = Dskip[i];

    float h[DS] = {};
    const size_t rowbase = (size_t)b * LL;

    for (int t = 0; t < LL; ++t) {
        const size_t row = rowbase + t;
        float d = delta[row * DI + i];
        float u = xcy[row * DI + i];
        const float* sp = ssm + row * 32;          // [B(16) | C(16)] wave-uniform
        float y = 0.f;
        #pragma unroll
        for (int s = 0; s < DS; ++s) {
            float e = d * a[s];
            e = fminf(fmaxf(e, -5.f), 5.f);
            float dA = __expf(e);
            h[s] = fmaf(dA, h[s], (d * sp[s]) * u);
            y = fmaf(h[s], sp[16 + s], y);
        }
        float res = xr[row * 2048 + DI + i];
        float g = res / (1.f + __expf(-res));
        xcy[row * DI + i] = (y + u * dsk) * g;
    }
}

// ---------------------------------------------------------------------------
// r = outp + clip(x); LayerNorm over 512; store per detected output dtype.
// ---------------------------------------------------------------------------
__global__ __launch_bounds__(256)
void ln_kernel(const float* __restrict__ outp, const float* __restrict__ x,
               const float* __restrict__ gamma, const float* __restrict__ beta,
               void* __restrict__ out, const int* __restrict__ flag)
{
    const int row = blockIdx.x;
    const int tid = threadIdx.x;

    float r[2];
    float sum = 0.f, ss = 0.f;
    #pragma unroll
    for (int q = 0; q < 2; ++q) {
        int j = tid + q * 256;
        float xv = x[(size_t)row * DM + j];
        xv = fminf(fmaxf(xv, -10.f), 10.f);
        float v = outp[(size_t)row * DM + j] + xv;
        r[q] = v;
        sum += v;
        ss = fmaf(v, v, ss);
    }
    #pragma unroll
    for (int off = 32; off >= 1; off >>= 1) {
        sum += __shfl_down(sum, off);
        ss  += __shfl_down(ss, off);
    }
    __shared__ float s1[4], s2[4];
    __shared__ float stats[2];
    int wid = tid >> 6, lane = tid & 63;
    if (lane == 0) { s1[wid] = sum; s2[wid] = ss; }
    __syncthreads();
    if (tid == 0) {
        float S = s1[0] + s1[1] + s1[2] + s1[3];
        float Q = s2[0] + s2[1] + s2[2] + s2[3];
        float mean = S / DM;
        float var = Q / DM - mean * mean;
        stats[0] = mean;
        stats[1] = rsqrtf(var + 1e-5f);
    }
    __syncthreads();
    float mean = stats[0], rstd = stats[1];
    const int isbf = *flag;
    #pragma unroll
    for (int q = 0; q < 2; ++q) {
        int j = tid + q * 256;
        float v = (r[q] - mean) * rstd * gamma[j] + beta[j];
        size_t o = (size_t)row * DM + j;
        if (isbf) ((bf16*)out)[o] = __float2bfloat16(v);
        else      ((float*)out)[o] = v;
    }
}

// ---------------------------------------------------------------------------
extern "C" void kernel_launch(void* const* d_in, const int* in_sizes, int n_in,
                              void* d_out, int out_size, void* d_ws, size_t ws_size,
                              hipStream_t stream)
{
    float* W = (float*)d_ws;
    float* xr   = W;                       // 4096x2048
    float* xc   = xr   + 8388608;          // 4096x1024
    float* dl   = xc   + 4194304;          // 4096x1024
    float* sm   = dl   + 4194304;          // 4096x32
    float* cx   = sm   + 131072;           // x        2097152
    float* cWin = cx   + 2097152;          // W_in     1048576
    float* ccw  = cWin + 1048576;          // conv_w   4096
    float* ccb  = ccw  + 4096;             // conv_b   1024
    float* cWx  = ccb  + 1024;             // W_x      32768
    float* cWdt = cWx  + 32768;            // W_dt     1048576
    float* cbdt = cWdt + 1048576;          // b_dt     1024
    float* cAlg = cbdt + 1024;             // A_log    16
    float* cDsk = cAlg + 16;               // D_skip   1024
    float* cWo  = cDsk + 1024;             // W_out    524288
    float* cgam = cWo  + 524288;           // gamma    512
    float* cbet = cgam + 512;              // beta     512
    int*   flag = (int*)(cbet + 512);

    // 0) dtype detection (probe W_dt = d_in[5])
    detect_dtype<<<1, 256, 0, stream>>>((const unsigned short*)d_in[5], flag);

    // 1) canonicalize all inputs to fp32
    const int nel[12] = {2097152, 1048576, 4096, 1024, 32768, 1048576,
                         1024, 16, 1024, 524288, 512, 512};
    float* dst[12] = {cx, cWin, ccw, ccb, cWx, cWdt, cbdt, cAlg, cDsk, cWo, cgam, cbet};
    for (int i = 0; i < 12; ++i)
        cvt_kernel<<<(nel[i] + 255) / 256, 256, 0, stream>>>(d_in[i], dst[i], nel[i], flag);

    // 2) x_and_res = clip(x) @ W_in          [4096,2048]
    gemm_tiled<<<dim3(2048 / 64, ROWS / 64), 256, 0, stream>>>(
        cx, cWin, nullptr, xr, ROWS, 2048, 512, 1);

    // 3) depthwise causal conv + SiLU -> xc
    conv_silu<<<dim3(ROWS * DI / 256), 256, 0, stream>>>(xr, ccw, ccb, xc);

    // 4) delta = xc @ W_dt + b_dt
    gemm_tiled<<<dim3(DI / 64, ROWS / 64), 256, 0, stream>>>(
        xc, cWdt, cbdt, dl, ROWS, DI, DI, 0);

    // 5) ssm = xc @ W_x                      [4096,32]
    gemm_tiled<<<dim3(1, ROWS / 64), 256, 0, stream>>>(
        xc, cWx, nullptr, sm, ROWS, 32, DI, 0);

    // 6) selective scan (+D skip, +silu(res) gating), in place over xc
    scan_kernel<<<dim3(DI / 64, BB), 64, 0, stream>>>(xc, dl, sm, xr, cAlg, cDsk);

    // 7) out_pre = y @ W_out                 [4096,512]  (reuses delta buffer)
    gemm_tiled<<<dim3(DM / 64, ROWS / 64), 256, 0, stream>>>(
        xc, cWo, nullptr, dl, ROWS, DM, DI, 0);

    // 8) LayerNorm(out_pre + clip(x)) -> out (dtype per flag)
    ln_kernel<<<ROWS, 256, 0, stream>>>(dl, cx, cgam, cbet, d_out, flag);
}

// Round 3
// 820.147 us; speedup vs baseline: 1.5650x; 1.5650x over previous
//
#include <hip/hip_runtime.h>
#include <hip/hip_bf16.h>

typedef __hip_bfloat16 bf16;

#define BB 4
#define LL 1024
#define DM 512
#define DS 16
#define DI 1024
#define ROWS (BB*LL)   // 4096
#define NC 32          // chunks over time
#define CT 32          // steps per chunk (NC*CT == LL)

__device__ __forceinline__ float b2f(bf16 v) { return __bfloat162float(v); }

// ---------------------------------------------------------------------------
// Dtype detector: probe W_dt (scale 0.02, |v| <= ~0.15 if bf16).
// bf16 data -> no 16-bit word has exponent >= 127. fp32 data -> odd words
// carry the fp32 exponent (~120) in their top bits -> ~half the words "bad".
// flag: 1 = bf16 inputs, 0 = fp32 inputs.
// ---------------------------------------------------------------------------
__global__ __launch_bounds__(256)
void detect_dtype(const unsigned short* __restrict__ p, int* __restrict__ flag)
{
    __shared__ int bad;
    if (threadIdx.x == 0) bad = 0;
    __syncthreads();
    int cnt = 0;
    #pragma unroll
    for (int r = 0; r < 16; ++r) {
        unsigned short u = p[threadIdx.x * 16 + r];
        int expo = (u >> 7) & 0xFF;
        if (expo >= 127) cnt++;
    }
    atomicAdd(&bad, cnt);
    __syncthreads();
    if (threadIdx.x == 0) *flag = (bad > 100) ? 0 : 1;
}

__global__ __launch_bounds__(256)
void cvt_kernel(const void* __restrict__ src, float* __restrict__ dst, int n,
                const int* __restrict__ flag)
{
    int i = blockIdx.x * 256 + threadIdx.x;
    if (i >= n) return;
    if (*flag) dst[i] = b2f(((const bf16*)src)[i]);
    else       dst[i] = ((const float*)src)[i];
}

// ---------------------------------------------------------------------------
// Tiled GEMM: C[M,N] = A[M,K] * B[K,N] (+bias), all fp32.
// ---------------------------------------------------------------------------
__global__ __launch_bounds__(256)
void gemm_tiled(const float* __restrict__ A, const float* __restrict__ Bw,
                const float* __restrict__ bias, float* __restrict__ C,
                int M, int N, int K, int clipA)
{
    __shared__ float As[16][68];
    __shared__ float Bs[16][68];

    const int tid = threadIdx.x;
    const int m0 = blockIdx.y * 64;
    const int n0 = blockIdx.x * 64;
    const int tx = tid & 15;
    const int ty = tid >> 4;

    float acc[4][4] = {};

    for (int k0 = 0; k0 < K; k0 += 16) {
        #pragma unroll
        for (int r = 0; r < 4; ++r) {
            int e = tid + r * 256;
            int m = e >> 4, k = e & 15;
            int gm = m0 + m, gk = k0 + k;
            float v = 0.f;
            if (gm < M && gk < K) v = A[(size_t)gm * K + gk];
            if (clipA) v = fminf(fmaxf(v, -10.f), 10.f);
            As[k][m] = v;
        }
        #pragma unroll
        for (int r = 0; r < 4; ++r) {
            int e = tid + r * 256;
            int k = e >> 6, n = e & 63;
            int gk = k0 + k, gn = n0 + n;
            float v = 0.f;
            if (gk < K && gn < N) v = Bw[(size_t)gk * N + gn];
            Bs[k][n] = v;
        }
        __syncthreads();

        #pragma unroll
        for (int kk = 0; kk < 16; ++kk) {
            float4 av = *(const float4*)&As[kk][ty * 4];
            float4 bv = *(const float4*)&Bs[kk][tx * 4];
            float a[4] = {av.x, av.y, av.z, av.w};
            float b[4] = {bv.x, bv.y, bv.z, bv.w};
            #pragma unroll
            for (int i = 0; i < 4; ++i)
                #pragma unroll
                for (int j = 0; j < 4; ++j)
                    acc[i][j] = fmaf(a[i], b[j], acc[i][j]);
        }
        __syncthreads();
    }

    #pragma unroll
    for (int i = 0; i < 4; ++i) {
        int gm = m0 + ty * 4 + i;
        if (gm >= M) continue;
        #pragma unroll
        for (int j = 0; j < 4; ++j) {
            int gn = n0 + tx * 4 + j;
            if (gn >= N) continue;
            float v = acc[i][j];
            if (bias) v += bias[gn];
            C[(size_t)gm * N + gn] = v;
        }
    }
}

// ---------------------------------------------------------------------------
// Depthwise causal conv (width 4) + SiLU.
// ---------------------------------------------------------------------------
__global__ __launch_bounds__(256)
void conv_silu(const float* __restrict__ xr, const float* __restrict__ cw,
               const float* __restrict__ cb, float* __restrict__ xc)
{
    int idx = blockIdx.x * 256 + threadIdx.x;
    int i = idx & (DI - 1);
    int row = idx >> 10;
    int t = row & (LL - 1);

    float w0 = cw[i * 4 + 0];
    float w1 = cw[i * 4 + 1];
    float w2 = cw[i * 4 + 2];
    float w3 = cw[i * 4 + 3];

    float acc = cb[i];
    const float* base = xr + (size_t)row * 2048 + i;
    if (t >= 3) acc = fmaf(base[-3 * 2048], w0, acc);
    if (t >= 2) acc = fmaf(base[-2 * 2048], w1, acc);
    if (t >= 1) acc = fmaf(base[-1 * 2048], w2, acc);
    acc = fmaf(base[0], w3, acc);

    xc[idx] = acc / (1.f + __expf(-acc));
}

// ---------------------------------------------------------------------------
// Chunked selective scan. h_t = a_t*h_{t-1} + w_t is associative:
// Pass A: per (b,i,c) run chunk from h=0, record P = prod(a), Q = h_end.
// Pass B: per (b,i,s) combine 32 chunk summaries -> h at each chunk start.
// Pass C: per (b,i,c) rerun chunk from true h_start, emit gated y in place.
// ---------------------------------------------------------------------------
__global__ __launch_bounds__(64)
void scan_chunk_summary(const float* __restrict__ xc, const float* __restrict__ delta,
                        const float* __restrict__ ssm, const float* __restrict__ A_log,
                        float* __restrict__ P, float* __restrict__ Q)
{
    const int b = blockIdx.z, c = blockIdx.y;
    const int i = blockIdx.x * 64 + threadIdx.x;

    float a[DS];
    #pragma unroll
    for (int s = 0; s < DS; ++s) a[s] = A_log[s];
    float h[DS] = {};
    float p[DS];
    #pragma unroll
    for (int s = 0; s < DS; ++s) p[s] = 1.f;

    const int row0 = b * LL + c * CT;
    for (int t = 0; t < CT; ++t) {
        const size_t row = row0 + t;
        float d = delta[row * DI + i];
        float u = xc[row * DI + i];
        const float* sp = ssm + row * 32;          // wave-uniform
        #pragma unroll
        for (int s = 0; s < DS; ++s) {
            float e = fminf(fmaxf(d * a[s], -5.f), 5.f);
            float dA = __expf(e);
            h[s] = fmaf(dA, h[s], (d * sp[s]) * u);
            p[s] *= dA;
        }
    }
    #pragma unroll
    for (int s = 0; s < DS; ++s) {
        size_t idx = ((size_t)((b * NC + c) * DS + s)) * DI + i;
        P[idx] = p[s];
        Q[idx] = h[s];
    }
}

__global__ __launch_bounds__(256)
void scan_chunk_combine(const float* __restrict__ P, const float* __restrict__ Q,
                        float* __restrict__ HS)
{
    int n = blockIdx.x * 256 + threadIdx.x;        // 4*16*1024 = 65536
    int i = n & (DI - 1);
    int s = (n >> 10) & (DS - 1);
    int b = n >> 14;
    float h = 0.f;
    for (int c = 0; c < NC; ++c) {
        size_t idx = ((size_t)((b * NC + c) * DS + s)) * DI + i;
        HS[idx] = h;
        h = fmaf(P[idx], h, Q[idx]);
    }
}

__global__ __launch_bounds__(64)
void scan_chunk_apply(float* __restrict__ xcy, const float* __restrict__ delta,
                      const float* __restrict__ ssm, const float* __restrict__ xr,
                      const float* __restrict__ A_log, const float* __restrict__ Dskip,
                      const float* __restrict__ HS)
{
    const int b = blockIdx.z, c = blockIdx.y;
    const int i = blockIdx.x * 64 + threadIdx.x;

    float a[DS];
    #pragma unroll
    for (int s = 0; s < DS; ++s) a[s] = A_log[s];
    float h[DS];
    #pragma unroll
    for (int s = 0; s < DS; ++s)
        h[s] = HS[((size_t)((b * NC + c) * DS + s)) * DI + i];
    const float dsk = Dskip[i];

    const int row0 = b * LL + c * CT;
    for (int t = 0; t < CT; ++t) {
        const size_t row = row0 + t;
        float d = delta[row * DI + i];
        float u = xcy[row * DI + i];
        const float* sp = ssm + row * 32;
        float y = 0.f;
        #pragma unroll
        for (int s = 0; s < DS; ++s) {
            float e = fminf(fmaxf(d * a[s], -5.f), 5.f);
            float dA = __expf(e);
            h[s] = fmaf(dA, h[s], (d * sp[s]) * u);
            y = fmaf(h[s], sp[DS + s], y);
        }
        float res = xr[row * 2048 + DI + i];
        float g = res / (1.f + __expf(-res));
        xcy[row * DI + i] = (y + u * dsk) * g;
    }
}

// ---------------------------------------------------------------------------
// r = outp + clip(x); LayerNorm over 512; store per detected output dtype.
// ---------------------------------------------------------------------------
__global__ __launch_bounds__(256)
void ln_kernel(const float* __restrict__ outp, const float* __restrict__ x,
               const float* __restrict__ gamma, const float* __restrict__ beta,
               void* __restrict__ out, const int* __restrict__ flag)
{
    const int row = blockIdx.x;
    const int tid = threadIdx.x;

    float r[2];
    float sum = 0.f, ss = 0.f;
    #pragma unroll
    for (int q = 0; q < 2; ++q) {
        int j = tid + q * 256;
        float xv = x[(size_t)row * DM + j];
        xv = fminf(fmaxf(xv, -10.f), 10.f);
        float v = outp[(size_t)row * DM + j] + xv;
        r[q] = v;
        sum += v;
        ss = fmaf(v, v, ss);
    }
    #pragma unroll
    for (int off = 32; off >= 1; off >>= 1) {
        sum += __shfl_down(sum, off);
        ss  += __shfl_down(ss, off);
    }
    __shared__ float s1[4], s2[4];
    __shared__ float stats[2];
    int wid = tid >> 6, lane = tid & 63;
    if (lane == 0) { s1[wid] = sum; s2[wid] = ss; }
    __syncthreads();
    if (tid == 0) {
        float S = s1[0] + s1[1] + s1[2] + s1[3];
        float Q = s2[0] + s2[1] + s2[2] + s2[3];
        float mean = S / DM;
        float var = Q / DM - mean * mean;
        stats[0] = mean;
        stats[1] = rsqrtf(var + 1e-5f);
    }
    __syncthreads();
    float mean = stats[0], rstd = stats[1];
    const int isbf = *flag;
    #pragma unroll
    for (int q = 0; q < 2; ++q) {
        int j = tid + q * 256;
        float v = (r[q] - mean) * rstd * gamma[j] + beta[j];
        size_t o = (size_t)row * DM + j;
        if (isbf) ((bf16*)out)[o] = __float2bfloat16(v);
        else      ((float*)out)[o] = v;
    }
}

// ---------------------------------------------------------------------------
extern "C" void kernel_launch(void* const* d_in, const int* in_sizes, int n_in,
                              void* d_out, int out_size, void* d_ws, size_t ws_size,
                              hipStream_t stream)
{
    float* W = (float*)d_ws;
    float* xr   = W;                       // 4096x2048
    float* xc   = xr   + 8388608;          // 4096x1024
    float* dl   = xc   + 4194304;          // 4096x1024
    float* sm   = dl   + 4194304;          // 4096x32
    float* cx   = sm   + 131072;           // x        2097152
    float* cWin = cx   + 2097152;          // W_in     1048576
    float* ccw  = cWin + 1048576;          // conv_w   4096
    float* ccb  = ccw  + 4096;             // conv_b   1024
    float* cWx  = ccb  + 1024;             // W_x      32768
    float* cWdt = cWx  + 32768;            // W_dt     1048576
    float* cbdt = cWdt + 1048576;          // b_dt     1024
    float* cAlg = cbdt + 1024;             // A_log    16
    float* cDsk = cAlg + 16;               // D_skip   1024
    float* cWo  = cDsk + 1024;             // W_out    524288
    float* cgam = cWo  + 524288;           // gamma    512
    float* cbet = cgam + 512;              // beta     512
    int*   flag = (int*)(cbet + 512);
    float* Pbuf = cbet + 512 + 16;         // 2097152  chunk products
    float* Qbuf = Pbuf + 2097152;          // 2097152  chunk offsets
    float* HS   = Qbuf + 2097152;          // 2097152  h at chunk starts

    // 0) dtype detection (probe W_dt = d_in[5])
    detect_dtype<<<1, 256, 0, stream>>>((const unsigned short*)d_in[5], flag);

    // 1) canonicalize all inputs to fp32
    const int nel[12] = {2097152, 1048576, 4096, 1024, 32768, 1048576,
                         1024, 16, 1024, 524288, 512, 512};
    float* dst[12] = {cx, cWin, ccw, ccb, cWx, cWdt, cbdt, cAlg, cDsk, cWo, cgam, cbet};
    for (int i = 0; i < 12; ++i)
        cvt_kernel<<<(nel[i] + 255) / 256, 256, 0, stream>>>(d_in[i], dst[i], nel[i], flag);

    // 2) x_and_res = clip(x) @ W_in          [4096,2048]
    gemm_tiled<<<dim3(2048 / 64, ROWS / 64), 256, 0, stream>>>(
        cx, cWin, nullptr, xr, ROWS, 2048, 512, 1);

    // 3) depthwise causal conv + SiLU -> xc
    conv_silu<<<dim3(ROWS * DI / 256), 256, 0, stream>>>(xr, ccw, ccb, xc);

    // 4) delta = xc @ W_dt + b_dt
    gemm_tiled<<<dim3(DI / 64, ROWS / 64), 256, 0, stream>>>(
        xc, cWdt, cbdt, dl, ROWS, DI, DI, 0);

    // 5) ssm = xc @ W_x                      [4096,32]
    gemm_tiled<<<dim3(1, ROWS / 64), 256, 0, stream>>>(
        xc, cWx, nullptr, sm, ROWS, 32, DI, 0);

    // 6) chunked selective scan (+D skip, +silu(res) gating), in place over xc
    scan_chunk_summary<<<dim3(DI / 64, NC, BB), 64, 0, stream>>>(
        xc, dl, sm, cAlg, Pbuf, Qbuf);
    scan_chunk_combine<<<dim3(BB * DS * DI / 256), 256, 0, stream>>>(Pbuf, Qbuf, HS);
    scan_chunk_apply<<<dim3(DI / 64, NC, BB), 64, 0, stream>>>(
        xc, dl, sm, xr, cAlg, cDsk, HS);

    // 7) out_pre = y @ W_out                 [4096,512]  (reuses delta buffer)
    gemm_tiled<<<dim3(DM / 64, ROWS / 64), 256, 0, stream>>>(
        xc, cWo, nullptr, dl, ROWS, DM, DI, 0);

    // 8) LayerNorm(out_pre + clip(x)) -> out (dtype per flag)
    ln_kernel<<<ROWS, 256, 0, stream>>>(dl, cx, cgam, cbet, d_out, flag);
}

// Round 4
// 281.933 us; speedup vs baseline: 4.5525x; 2.9090x over previous
//
#include <hip/hip_runtime.h>
#include <hip/hip_bf16.h>

typedef __hip_bfloat16 bf16;
typedef unsigned short ushort_t;
typedef __attribute__((ext_vector_type(8))) __bf16 bf16x8;
typedef __attribute__((ext_vector_type(4))) float f32x4;

#define BB 4
#define LL 1024
#define DM 512
#define DS 16
#define DI 1024
#define ROWS 4096
#define NC 32
#define CT 32
#define NDTX 1152   // padded N for the fused [delta | ssm] GEMM (9*128)

__device__ __forceinline__ float b2f(bf16 v) { return __bfloat162float(v); }

__device__ __forceinline__ float load_flag(const void* src, int i, int isbf)
{
    return isbf ? b2f(((const bf16*)src)[i]) : ((const float*)src)[i];
}

// ---------------------------------------------------------------------------
// Dtype detector (probe W_dt): bf16 data has no 16-bit word with exp>=127;
// fp32 data read as 16-bit words has ~half "bad". flag: 1=bf16, 0=fp32.
// ---------------------------------------------------------------------------
__global__ __launch_bounds__(256)
void detect_dtype(const ushort_t* __restrict__ p, int* __restrict__ flag)
{
    __shared__ int bad;
    if (threadIdx.x == 0) bad = 0;
    __syncthreads();
    int cnt = 0;
    #pragma unroll
    for (int r = 0; r < 16; ++r) {
        ushort_t u = p[threadIdx.x * 16 + r];
        if (((u >> 7) & 0xFF) >= 127) cnt++;
    }
    atomicAdd(&bad, cnt);
    __syncthreads();
    if (threadIdx.x == 0) *flag = (bad > 100) ? 0 : 1;
}

__global__ __launch_bounds__(256)
void cvt_kernel(const void* __restrict__ src, float* __restrict__ dst, int n,
                const int* __restrict__ flag)
{
    int i = blockIdx.x * 256 + threadIdx.x;
    if (i >= n) return;
    dst[i] = load_flag(src, i, *flag);
}

// x -> clipped fp32 copy (for LN residual) + clipped bf16 copy (GEMM1 A-operand)
__global__ __launch_bounds__(256)
void pack_x(const void* __restrict__ src, float* __restrict__ cx,
            bf16* __restrict__ xbf, const int* __restrict__ flag)
{
    int i = blockIdx.x * 256 + threadIdx.x;   // ROWS*DM
    float v = load_flag(src, i, *flag);
    v = fminf(fmaxf(v, -10.f), 10.f);
    cx[i] = v;
    xbf[i] = __float2bfloat16(v);
}

// Transpose src[K][Nsrc] -> dst[R][K] bf16 (rows r>=Nsrc are zero-filled).
// K is a power of two (kshift = log2 K).
__global__ __launch_bounds__(256)
void transpose_bf16(const void* __restrict__ src, bf16* __restrict__ dst,
                    int Nsrc, int K, int kshift, int total,
                    const int* __restrict__ flag)
{
    int idx = blockIdx.x * 256 + threadIdx.x;   // R*K
    if (idx >= total) return;
    int n = idx >> kshift;
    int k = idx & (K - 1);
    float v = (n < Nsrc) ? load_flag(src, k * Nsrc + n, *flag) : 0.f;
    dst[idx] = __float2bfloat16(v);
}

// bias vector for fused dtx GEMM: [b_dt | zeros] length NDTX
__global__ __launch_bounds__(256)
void build_bias_dtx(const void* __restrict__ b_dt, float* __restrict__ bias,
                    const int* __restrict__ flag)
{
    int i = blockIdx.x * 256 + threadIdx.x;
    if (i >= NDTX) return;
    bias[i] = (i < DI) ? load_flag(b_dt, i, *flag) : 0.f;
}

// ---------------------------------------------------------------------------
// MFMA bf16 GEMM: C[M][N] = A[M][K] * Bt[N][K]^T (+bias), fp32 out.
// 128x128 tile, 4 waves, 4x4 16x16x32 frags/wave, BK=32,
// global_load_lds width-16 staging with XOR k-chunk swizzle.
// M,N,K multiples of 128/128/32; pointers 16B-aligned.
// ---------------------------------------------------------------------------
__device__ __forceinline__ void gload16(const bf16* g, ushort_t* l)
{
    __builtin_amdgcn_global_load_lds(
        (const __attribute__((address_space(1))) void*)g,
        (__attribute__((address_space(3))) void*)l, 16, 0, 0);
}

__global__ __launch_bounds__(256)
void gemm_mfma(const bf16* __restrict__ A, const bf16* __restrict__ Bt,
               const float* __restrict__ bias, float* __restrict__ C,
               int M, int N, int K)
{
    __shared__ ushort_t As[128 * 32];
    __shared__ ushort_t Bs[128 * 32];

    const int tid = threadIdx.x;
    const int lane = tid & 63;
    const int w = tid >> 6;
    const int wr = w >> 1, wc = w & 1;
    const int m0 = blockIdx.y * 128;
    const int n0 = blockIdx.x * 128;

    // staging: 16B block p = q*256+tid; tile row = p>>2; swizzled chunk
    // position pos = p&3 holds source k-chunk k8 = (pos - row) & 3
    const int pa0 = tid, pa1 = 256 + tid;
    const int ra0 = pa0 >> 2, ka0 = ((pa0 & 3) - ra0) & 3;
    const int ra1 = pa1 >> 2, ka1 = ((pa1 & 3) - ra1) & 3;

    const bf16* Ag0 = A + (size_t)(m0 + ra0) * K + ka0 * 8;
    const bf16* Ag1 = A + (size_t)(m0 + ra1) * K + ka1 * 8;
    const bf16* Bg0 = Bt + (size_t)(n0 + ra0) * K + ka0 * 8;
    const bf16* Bg1 = Bt + (size_t)(n0 + ra1) * K + ka1 * 8;

    ushort_t* Al0 = &As[w * 512];
    ushort_t* Al1 = &As[2048 + w * 512];
    ushort_t* Bl0 = &Bs[w * 512];
    ushort_t* Bl1 = &Bs[2048 + w * 512];

    f32x4 acc[4][4];
    #pragma unroll
    for (int i = 0; i < 4; ++i)
        #pragma unroll
        for (int j = 0; j < 4; ++j)
            acc[i][j] = (f32x4){0.f, 0.f, 0.f, 0.f};

    const int ko = lane >> 4;     // k-chunk 0..3
    const int ml = lane & 15;

    for (int k0 = 0; k0 < K; k0 += 32) {
        gload16(Ag0 + k0, Al0);
        gload16(Ag1 + k0, Al1);
        gload16(Bg0 + k0, Bl0);
        gload16(Bg1 + k0, Bl1);
        __syncthreads();          // drains vmcnt before compute

        bf16x8 af[4], bfr[4];
        #pragma unroll
        for (int i = 0; i < 4; ++i) {
            int m = wr * 64 + i * 16 + ml;
            af[i] = *(const bf16x8*)&As[(m * 4 + ((ko + m) & 3)) * 8];
            int n = wc * 64 + i * 16 + ml;
            bfr[i] = *(const bf16x8*)&Bs[(n * 4 + ((ko + n) & 3)) * 8];
        }
        #pragma unroll
        for (int i = 0; i < 4; ++i)
            #pragma unroll
            for (int j = 0; j < 4; ++j)
                acc[i][j] = __builtin_amdgcn_mfma_f32_16x16x32_bf16(
                    af[i], bfr[j], acc[i][j], 0, 0, 0);
        __syncthreads();          // before next overwrite
    }

    // C/D layout: col = lane&15, row = (lane>>4)*4 + reg   [m89/m91]
    const int rq = lane >> 4;
    #pragma unroll
    for (int j = 0; j < 4; ++j) {
        int n = n0 + wc * 64 + j * 16 + ml;
        float bv = bias ? bias[n] : 0.f;
        #pragma unroll
        for (int i = 0; i < 4; ++i) {
            int mb = m0 + wr * 64 + i * 16 + rq * 4;
            #pragma unroll
            for (int r = 0; r < 4; ++r)
                C[(size_t)(mb + r) * N + n] = acc[i][j][r] + bv;
        }
    }
}

// ---------------------------------------------------------------------------
// Depthwise causal conv (width 4) + SiLU -> bf16 xc.
// ---------------------------------------------------------------------------
__global__ __launch_bounds__(256)
void conv_silu(const float* __restrict__ xr, const float* __restrict__ cw,
               const float* __restrict__ cb, bf16* __restrict__ xcb)
{
    int idx = blockIdx.x * 256 + threadIdx.x;
    int i = idx & (DI - 1);
    int row = idx >> 10;
    int t = row & (LL - 1);

    float w0 = cw[i * 4 + 0];
    float w1 = cw[i * 4 + 1];
    float w2 = cw[i * 4 + 2];
    float w3 = cw[i * 4 + 3];

    float acc = cb[i];
    const float* base = xr + (size_t)row * 2048 + i;
    if (t >= 3) acc = fmaf(base[-3 * 2048], w0, acc);
    if (t >= 2) acc = fmaf(base[-2 * 2048], w1, acc);
    if (t >= 1) acc = fmaf(base[-1 * 2048], w2, acc);
    acc = fmaf(base[0], w3, acc);

    xcb[idx] = __float2bfloat16(acc / (1.f + __expf(-acc)));
}

// ---------------------------------------------------------------------------
// Chunked selective scan (3 passes). delta at dlx[row*NDTX + i];
// ssm (B|C) at dlx[row*NDTX + 1024 + s]; u from bf16 xc.
// ---------------------------------------------------------------------------
__global__ __launch_bounds__(64)
void scan_chunk_summary(const bf16* __restrict__ xcb, const float* __restrict__ dlx,
                        const float* __restrict__ A_log,
                        float* __restrict__ P, float* __restrict__ Q)
{
    const int b = blockIdx.z, c = blockIdx.y;
    const int i = blockIdx.x * 64 + threadIdx.x;

    float a[DS];
    #pragma unroll
    for (int s = 0; s < DS; ++s) a[s] = A_log[s];
    float h[DS] = {};
    float p[DS];
    #pragma unroll
    for (int s = 0; s < DS; ++s) p[s] = 1.f;

    const int row0 = b * LL + c * CT;
    for (int t = 0; t < CT; ++t) {
        const size_t row = row0 + t;
        float d = dlx[row * NDTX + i];
        float u = b2f(xcb[row * DI + i]);
        const float* sp = dlx + row * NDTX + 1024;   // wave-uniform
        #pragma unroll
        for (int s = 0; s < DS; ++s) {
            float e = fminf(fmaxf(d * a[s], -5.f), 5.f);
            float dA = __expf(e);
            h[s] = fmaf(dA, h[s], (d * sp[s]) * u);
            p[s] *= dA;
        }
    }
    #pragma unroll
    for (int s = 0; s < DS; ++s) {
        size_t idx = ((size_t)((b * NC + c) * DS + s)) * DI + i;
        P[idx] = p[s];
        Q[idx] = h[s];
    }
}

__global__ __launch_bounds__(256)
void scan_chunk_combine(const float* __restrict__ P, const float* __restrict__ Q,
                        float* __restrict__ HS)
{
    int n = blockIdx.x * 256 + threadIdx.x;        // 65536
    int i = n & (DI - 1);
    int s = (n >> 10) & (DS - 1);
    int b = n >> 14;
    float h = 0.f;
    for (int c = 0; c < NC; ++c) {
        size_t idx = ((size_t)((b * NC + c) * DS + s)) * DI + i;
        HS[idx] = h;
        h = fmaf(P[idx], h, Q[idx]);
    }
}

__global__ __launch_bounds__(64)
void scan_chunk_apply(const bf16* __restrict__ xcb, const float* __restrict__ dlx,
                      const float* __restrict__ xr, const float* __restrict__ A_log,
                      const float* __restrict__ Dskip, const float* __restrict__ HS,
                      bf16* __restrict__ ybf)
{
    const int b = blockIdx.z, c = blockIdx.y;
    const int i = blockIdx.x * 64 + threadIdx.x;

    float a[DS];
    #pragma unroll
    for (int s = 0; s < DS; ++s) a[s] = A_log[s];
    float h[DS];
    #pragma unroll
    for (int s = 0; s < DS; ++s)
        h[s] = HS[((size_t)((b * NC + c) * DS + s)) * DI + i];
    const float dsk = Dskip[i];

    const int row0 = b * LL + c * CT;
    for (int t = 0; t < CT; ++t) {
        const size_t row = row0 + t;
        float d = dlx[row * NDTX + i];
        float u = b2f(xcb[row * DI + i]);
        const float* sp = dlx + row * NDTX + 1024;
        float y = 0.f;
        #pragma unroll
        for (int s = 0; s < DS; ++s) {
            float e = fminf(fmaxf(d * a[s], -5.f), 5.f);
            float dA = __expf(e);
            h[s] = fmaf(dA, h[s], (d * sp[s]) * u);
            y = fmaf(h[s], sp[DS + s], y);
        }
        float res = xr[row * 2048 + DI + i];
        float g = res / (1.f + __expf(-res));
        ybf[row * DI + i] = __float2bfloat16((y + u * dsk) * g);
    }
}

// ---------------------------------------------------------------------------
// r = outp + clip(x); LayerNorm over 512; store per detected output dtype.
// ---------------------------------------------------------------------------
__global__ __launch_bounds__(256)
void ln_kernel(const float* __restrict__ outp, const float* __restrict__ x,
               const float* __restrict__ gamma, const float* __restrict__ beta,
               void* __restrict__ out, const int* __restrict__ flag)
{
    const int row = blockIdx.x;
    const int tid = threadIdx.x;

    float r[2];
    float sum = 0.f, ss = 0.f;
    #pragma unroll
    for (int q = 0; q < 2; ++q) {
        int j = tid + q * 256;
        float v = outp[(size_t)row * DM + j] + x[(size_t)row * DM + j];
        r[q] = v;
        sum += v;
        ss = fmaf(v, v, ss);
    }
    #pragma unroll
    for (int off = 32; off >= 1; off >>= 1) {
        sum += __shfl_down(sum, off);
        ss  += __shfl_down(ss, off);
    }
    __shared__ float s1[4], s2[4];
    __shared__ float stats[2];
    int wid = tid >> 6, lane = tid & 63;
    if (lane == 0) { s1[wid] = sum; s2[wid] = ss; }
    __syncthreads();
    if (tid == 0) {
        float S = s1[0] + s1[1] + s1[2] + s1[3];
        float Qq = s2[0] + s2[1] + s2[2] + s2[3];
        float mean = S / DM;
        float var = Qq / DM - mean * mean;
        stats[0] = mean;
        stats[1] = rsqrtf(var + 1e-5f);
    }
    __syncthreads();
    float mean = stats[0], rstd = stats[1];
    const int isbf = *flag;
    #pragma unroll
    for (int q = 0; q < 2; ++q) {
        int j = tid + q * 256;
        float v = (r[q] - mean) * rstd * gamma[j] + beta[j];
        size_t o = (size_t)row * DM + j;
        if (isbf) ((bf16*)out)[o] = __float2bfloat16(v);
        else      ((float*)out)[o] = v;
    }
}

// ---------------------------------------------------------------------------
extern "C" void kernel_launch(void* const* d_in, const int* in_sizes, int n_in,
                              void* d_out, int out_size, void* d_ws, size_t ws_size,
                              hipStream_t stream)
{
    float* W = (float*)d_ws;
    float* xr   = W;                       // 4096x2048        8388608
    float* dlx  = xr   + 8388608;          // 4096x1152        4718592 (delta|ssm)
    float* cx   = dlx  + 4718592;          // 4096x512         2097152 (clipped x fp32)
    float* Pbuf = cx   + 2097152;          // 2097152 chunk products; outp aliases later
    float* Qbuf = Pbuf + 2097152;          // 2097152
    float* HS   = Qbuf + 2097152;          // 2097152
    float* ccw  = HS   + 2097152;          // conv_w 4096
    float* ccb  = ccw  + 4096;             // conv_b 1024
    float* cAlg = ccb  + 1024;             // A_log 16
    float* cDsk = cAlg + 16;               // D_skip 1024
    float* cgam = cDsk + 1024;             // gamma 512
    float* cbet = cgam + 512;              // beta 512
    float* bdtx = cbet + 512;              // bias_dtx 1152
    int*   flag = (int*)(bdtx + 1152);
    bf16*  xbf  = (bf16*)(flag + 16);      // 4096x512   clipped x bf16
    bf16*  xcb  = xbf  + 2097152;          // 4096x1024  conv+silu bf16
    bf16*  ybf  = xcb  + 4194304;          // 4096x1024  gated y bf16
    bf16*  WtIn = ybf  + 4194304;          // 2048x512   W_in^T
    bf16*  WtDtx= WtIn + 1048576;          // 1152x1024  [W_dt|W_x|0]^T
    bf16*  WtOut= WtDtx+ 1179648;          // 512x1024   W_out^T
    float* outp = Pbuf;                    // 4096x512 fp32 (aliases dead Pbuf)

    // 0) dtype detection (probe W_dt = d_in[5])
    detect_dtype<<<1, 256, 0, stream>>>((const ushort_t*)d_in[5], flag);

    // 1) small params -> fp32
    cvt_kernel<<<16, 256, 0, stream>>>(d_in[2],  ccw, 4096, flag);
    cvt_kernel<<<4, 256, 0, stream>>>(d_in[3],  ccb, 1024, flag);
    cvt_kernel<<<1, 256, 0, stream>>>(d_in[7],  cAlg, 16, flag);
    cvt_kernel<<<4, 256, 0, stream>>>(d_in[8],  cDsk, 1024, flag);
    cvt_kernel<<<2, 256, 0, stream>>>(d_in[10], cgam, 512, flag);
    cvt_kernel<<<2, 256, 0, stream>>>(d_in[11], cbet, 512, flag);
    build_bias_dtx<<<(NDTX + 255) / 256, 256, 0, stream>>>(d_in[6], bdtx, flag);

    // 2) x -> clipped fp32 + bf16
    pack_x<<<ROWS * DM / 256, 256, 0, stream>>>(d_in[0], cx, xbf, flag);

    // 3) weight transposes -> bf16 [N][K]
    transpose_bf16<<<(2048 * 512) / 256, 256, 0, stream>>>(
        d_in[1], WtIn, 2048, 512, 9, 2048 * 512, flag);                 // W_in
    transpose_bf16<<<(1024 * 1024) / 256, 256, 0, stream>>>(
        d_in[5], WtDtx, 1024, 1024, 10, 1024 * 1024, flag);             // W_dt
    transpose_bf16<<<(128 * 1024) / 256, 256, 0, stream>>>(
        d_in[4], WtDtx + 1024 * 1024, 32, 1024, 10, 128 * 1024, flag);  // W_x (+zero pad)
    transpose_bf16<<<(512 * 1024) / 256, 256, 0, stream>>>(
        d_in[9], WtOut, 512, 1024, 10, 512 * 1024, flag);               // W_out

    // 4) x_and_res = clip(x) @ W_in        [4096,2048] = [4096,512]x[512,2048]
    gemm_mfma<<<dim3(2048 / 128, ROWS / 128), 256, 0, stream>>>(
        xbf, WtIn, nullptr, xr, ROWS, 2048, 512);

    // 5) depthwise causal conv + SiLU -> bf16 xc
    conv_silu<<<ROWS * DI / 256, 256, 0, stream>>>(xr, ccw, ccb, xcb);

    // 6) [delta | ssm] = xc @ [W_dt | W_x] (+[b_dt|0])   [4096,1152]
    gemm_mfma<<<dim3(NDTX / 128, ROWS / 128), 256, 0, stream>>>(
        xcb, WtDtx, bdtx, dlx, ROWS, NDTX, DI);

    // 7) chunked selective scan -> gated bf16 y
    scan_chunk_summary<<<dim3(DI / 64, NC, BB), 64, 0, stream>>>(
        xcb, dlx, cAlg, Pbuf, Qbuf);
    scan_chunk_combine<<<BB * DS * DI / 256, 256, 0, stream>>>(Pbuf, Qbuf, HS);
    scan_chunk_apply<<<dim3(DI / 64, NC, BB), 64, 0, stream>>>(
        xcb, dlx, xr, cAlg, cDsk, HS, ybf);

    // 8) out_pre = y @ W_out               [4096,512]
    gemm_mfma<<<dim3(DM / 128, ROWS / 128), 256, 0, stream>>>(
        ybf, WtOut, nullptr, outp, ROWS, DM, DI);

    // 9) LayerNorm(out_pre + clip(x)) -> out (dtype per flag)
    ln_kernel<<<ROWS, 256, 0, stream>>>(outp, cx, cgam, cbet, d_out, flag);
}

// Round 5
// 243.436 us; speedup vs baseline: 5.2724x; 1.1581x over previous
//
#include <hip/hip_runtime.h>
#include <hip/hip_bf16.h>

typedef __hip_bfloat16 bf16;
typedef unsigned short ushort_t;
typedef __attribute__((ext_vector_type(8))) __bf16 bf16x8;
typedef __attribute__((ext_vector_type(4))) float f32x4;

#define BB 4
#define LL 1024
#define DM 512
#define DS 16
#define DI 1024
#define ROWS 4096
#define NC 64
#define CT 16
#define NDTX 1152   // padded N for the fused [delta | ssm] GEMM (9*128)

__device__ __forceinline__ float b2f(bf16 v) { return __bfloat162float(v); }

__device__ __forceinline__ float load_flag(const void* src, int i, int isbf)
{
    return isbf ? b2f(((const bf16*)src)[i]) : ((const float*)src)[i];
}

// ---------------------------------------------------------------------------
// Dtype detector (probe W_dt): bf16 data has no 16-bit word with exp>=127;
// fp32 data read as 16-bit words has ~half "bad". flag: 1=bf16, 0=fp32.
// ---------------------------------------------------------------------------
__global__ __launch_bounds__(256)
void detect_dtype(const ushort_t* __restrict__ p, int* __restrict__ flag)
{
    __shared__ int bad;
    if (threadIdx.x == 0) bad = 0;
    __syncthreads();
    int cnt = 0;
    #pragma unroll
    for (int r = 0; r < 16; ++r) {
        ushort_t u = p[threadIdx.x * 16 + r];
        if (((u >> 7) & 0xFF) >= 127) cnt++;
    }
    atomicAdd(&bad, cnt);
    __syncthreads();
    if (threadIdx.x == 0) *flag = (bad > 100) ? 0 : 1;
}

// ---------------------------------------------------------------------------
// All small-parameter conversions + dtx bias build + WtDtx zero-pad in one.
// Ranges: ccw[0,4096) ccb[..5120) cAlg[..5136) cDsk[..6160) cgam[..6672)
//         cbet[..7184) bdtx[..8336) WtDtx pad rows 1056..1151 [..106640)
// ---------------------------------------------------------------------------
__global__ __launch_bounds__(256)
void prep_small(const void* cw, const void* cb, const void* Alog,
                const void* Dsk, const void* gam, const void* bet,
                const void* bdt,
                float* __restrict__ ccw, float* __restrict__ ccb,
                float* __restrict__ cAlg, float* __restrict__ cDsk,
                float* __restrict__ cgam, float* __restrict__ cbet,
                float* __restrict__ bdtx, bf16* __restrict__ padWtDtx,
                const int* __restrict__ flag)
{
    int i = blockIdx.x * 256 + threadIdx.x;
    int isbf = *flag;
    if (i < 4096)        ccw[i] = load_flag(cw, i, isbf);
    else if (i < 5120)   ccb[i - 4096] = load_flag(cb, i - 4096, isbf);
    else if (i < 5136)   cAlg[i - 5120] = load_flag(Alog, i - 5120, isbf);
    else if (i < 6160)   cDsk[i - 5136] = load_flag(Dsk, i - 5136, isbf);
    else if (i < 6672)   cgam[i - 6160] = load_flag(gam, i - 6160, isbf);
    else if (i < 7184)   cbet[i - 6672] = load_flag(bet, i - 6672, isbf);
    else if (i < 8336) {
        int j = i - 7184;
        bdtx[j] = (j < DI) ? load_flag(bdt, j, isbf) : 0.f;
    } else if (i < 106640) {
        padWtDtx[i - 8336] = __float2bfloat16(0.f);
    }
}

// x -> clipped bf16 (GEMM1 A-operand)
__global__ __launch_bounds__(256)
void pack_x(const void* __restrict__ src, bf16* __restrict__ xbf,
            const int* __restrict__ flag)
{
    int i = blockIdx.x * 256 + threadIdx.x;   // ROWS*DM
    float v = load_flag(src, i, *flag);
    v = fminf(fmaxf(v, -10.f), 10.f);
    xbf[i] = __float2bfloat16(v);
}

// ---------------------------------------------------------------------------
// All weight transposes in one kernel. LDS 32x32 tile (+1 pad), coalesced
// reads and writes. src[K][Nsrc] -> dst[Nsrc][K] bf16.
// Tile ranges: W_in 1024 | W_dt 1024 | W_x 32 | W_out 512  (total 2592)
// ---------------------------------------------------------------------------
__global__ __launch_bounds__(256)
void transpose_all(const void* Win, const void* Wdt, const void* Wx,
                   const void* Wout, bf16* __restrict__ WtIn,
                   bf16* __restrict__ WtDtx, bf16* __restrict__ WtOut,
                   const int* __restrict__ flag)
{
    int tb = blockIdx.x;
    const void* src; bf16* dst; int K, Nsrc, tpr;
    if (tb < 1024)      { src = Win;  dst = WtIn;            K = 512;  Nsrc = 2048; tpr = 64; }
    else if (tb < 2048) { tb -= 1024; src = Wdt; dst = WtDtx; K = 1024; Nsrc = 1024; tpr = 32; }
    else if (tb < 2080) { tb -= 2048; src = Wx;  dst = WtDtx + 1024 * 1024; K = 1024; Nsrc = 32; tpr = 1; }
    else                { tb -= 2080; src = Wout; dst = WtOut; K = 1024; Nsrc = 512;  tpr = 16; }
    int k0 = (tb / tpr) * 32, n0 = (tb % tpr) * 32;

    __shared__ float tile[32][33];
    int tx = threadIdx.x & 31, ty = threadIdx.x >> 5;
    int isbf = *flag;
    #pragma unroll
    for (int j = 0; j < 4; ++j)
        tile[ty + 8 * j][tx] = load_flag(src, (k0 + ty + 8 * j) * Nsrc + n0 + tx, isbf);
    __syncthreads();
    #pragma unroll
    for (int j = 0; j < 4; ++j)
        dst[(size_t)(n0 + ty + 8 * j) * K + k0 + tx] = __float2bfloat16(tile[tx][ty + 8 * j]);
}

// ---------------------------------------------------------------------------
// MFMA bf16 GEMM: C[M][N] = A[M][K] * Bt[N][K]^T (+bias).
// TM x 128 tile, 4 waves (2x2), 16x16x32 frags, BK=32,
// global_load_lds width-16 staging with XOR k-chunk swizzle.
// TM in {128, 64}. OBF: store bf16 (else fp32).
// ---------------------------------------------------------------------------
__device__ __forceinline__ void gload16(const bf16* g, ushort_t* l)
{
    __builtin_amdgcn_global_load_lds(
        (const __attribute__((address_space(1))) void*)g,
        (__attribute__((address_space(3))) void*)l, 16, 0, 0);
}

template <int TM, bool OBF>
__global__ __launch_bounds__(256)
void gemm_mfma(const bf16* __restrict__ A, const bf16* __restrict__ Bt,
               const float* __restrict__ bias, void* __restrict__ Cv,
               int M, int N, int K)
{
    constexpr int MI = TM / 32;        // m-frags per wave
    __shared__ ushort_t As[TM * 32];
    __shared__ ushort_t Bs[128 * 32];

    const int tid = threadIdx.x;
    const int lane = tid & 63;
    const int w = tid >> 6;
    const int wr = w >> 1, wc = w & 1;
    const int mBase = wr * (TM / 2);
    const int m0 = blockIdx.y * TM;
    const int n0 = blockIdx.x * 128;

    // staging: 16B block p; tile row = p>>2; position p&3 holds k-chunk ((p&3)-row)&3
    const int pa0 = tid, pa1 = 256 + tid;
    const int ra0 = pa0 >> 2, ka0 = ((pa0 & 3) - ra0) & 3;
    const int ra1 = pa1 >> 2, ka1 = ((pa1 & 3) - ra1) & 3;

    const bf16* Ag0 = A + (size_t)(m0 + ra0) * K + ka0 * 8;
    const bf16* Ag1 = A + (size_t)(m0 + ra1) * K + ka1 * 8;   // TM==128 only
    const bf16* Bg0 = Bt + (size_t)(n0 + ra0) * K + ka0 * 8;
    const bf16* Bg1 = Bt + (size_t)(n0 + ra1) * K + ka1 * 8;

    ushort_t* Al0 = &As[w * 512];
    ushort_t* Al1 = &As[2048 + w * 512];
    ushort_t* Bl0 = &Bs[w * 512];
    ushort_t* Bl1 = &Bs[2048 + w * 512];

    f32x4 acc[MI][4];
    #pragma unroll
    for (int i = 0; i < MI; ++i)
        #pragma unroll
        for (int j = 0; j < 4; ++j)
            acc[i][j] = (f32x4){0.f, 0.f, 0.f, 0.f};

    const int ko = lane >> 4;
    const int ml = lane & 15;

    for (int k0 = 0; k0 < K; k0 += 32) {
        gload16(Ag0 + k0, Al0);
        if (TM == 128) gload16(Ag1 + k0, Al1);
        gload16(Bg0 + k0, Bl0);
        gload16(Bg1 + k0, Bl1);
        __syncthreads();

        bf16x8 af[MI], bfr[4];
        #pragma unroll
        for (int i = 0; i < MI; ++i) {
            int m = mBase + i * 16 + ml;
            af[i] = *(const bf16x8*)&As[(m * 4 + ((ko + m) & 3)) * 8];
        }
        #pragma unroll
        for (int j = 0; j < 4; ++j) {
            int n = wc * 64 + j * 16 + ml;
            bfr[j] = *(const bf16x8*)&Bs[(n * 4 + ((ko + n) & 3)) * 8];
        }
        #pragma unroll
        for (int i = 0; i < MI; ++i)
            #pragma unroll
            for (int j = 0; j < 4; ++j)
                acc[i][j] = __builtin_amdgcn_mfma_f32_16x16x32_bf16(
                    af[i], bfr[j], acc[i][j], 0, 0, 0);
        __syncthreads();
    }

    // C/D layout: col = lane&15, row = (lane>>4)*4 + reg
    const int rq = lane >> 4;
    #pragma unroll
    for (int j = 0; j < 4; ++j) {
        int n = n0 + wc * 64 + j * 16 + ml;
        float bv = bias ? bias[n] : 0.f;
        #pragma unroll
        for (int i = 0; i < MI; ++i) {
            int mb = m0 + mBase + i * 16 + rq * 4;
            #pragma unroll
            for (int r = 0; r < 4; ++r) {
                float v = acc[i][j][r] + bv;
                if (OBF) ((bf16*)Cv)[(size_t)(mb + r) * N + n] = __float2bfloat16(v);
                else     ((float*)Cv)[(size_t)(mb + r) * N + n] = v;
            }
        }
    }
}

// ---------------------------------------------------------------------------
// Depthwise causal conv (width 4) + SiLU. xrb bf16 [ROWS][2048]; xp = cols<DI.
// ---------------------------------------------------------------------------
__global__ __launch_bounds__(256)
void conv_silu(const bf16* __restrict__ xrb, const float* __restrict__ cw,
               const float* __restrict__ cb, bf16* __restrict__ xcb)
{
    int idx = blockIdx.x * 256 + threadIdx.x;
    int i = idx & (DI - 1);
    int row = idx >> 10;
    int t = row & (LL - 1);

    float w0 = cw[i * 4 + 0];
    float w1 = cw[i * 4 + 1];
    float w2 = cw[i * 4 + 2];
    float w3 = cw[i * 4 + 3];

    float acc = cb[i];
    const bf16* base = xrb + (size_t)row * 2048 + i;
    if (t >= 3) acc = fmaf(b2f(base[-3 * 2048]), w0, acc);
    if (t >= 2) acc = fmaf(b2f(base[-2 * 2048]), w1, acc);
    if (t >= 1) acc = fmaf(b2f(base[-1 * 2048]), w2, acc);
    acc = fmaf(b2f(base[0]), w3, acc);

    xcb[idx] = __float2bfloat16(acc / (1.f + __expf(-acc)));
}

// ---------------------------------------------------------------------------
// Chunked selective scan (3 passes). delta at dlx[row*NDTX+i];
// ssm (B|C) at dlx[row*NDTX+1024+s] (wave-uniform); u from bf16 xc.
// ---------------------------------------------------------------------------
__global__ __launch_bounds__(64)
void scan_chunk_summary(const bf16* __restrict__ xcb, const float* __restrict__ dlx,
                        const float* __restrict__ A_log,
                        float* __restrict__ P, float* __restrict__ Q)
{
    const int b = blockIdx.z, c = blockIdx.y;
    const int i = blockIdx.x * 64 + threadIdx.x;

    float a[DS];
    #pragma unroll
    for (int s = 0; s < DS; ++s) a[s] = A_log[s];
    float h[DS] = {};
    float p[DS];
    #pragma unroll
    for (int s = 0; s < DS; ++s) p[s] = 1.f;

    const int row0 = b * LL + c * CT;
    for (int t = 0; t < CT; ++t) {
        const size_t row = row0 + t;
        float d = dlx[row * NDTX + i];
        float u = b2f(xcb[row * DI + i]);
        const float* sp = dlx + row * NDTX + 1024;
        #pragma unroll
        for (int s = 0; s < DS; ++s) {
            float e = fminf(fmaxf(d * a[s], -5.f), 5.f);
            float dA = __expf(e);
            h[s] = fmaf(dA, h[s], (d * sp[s]) * u);
            p[s] *= dA;
        }
    }
    #pragma unroll
    for (int s = 0; s < DS; ++s) {
        size_t idx = ((size_t)((b * NC + c) * DS + s)) * DI + i;
        P[idx] = p[s];
        Q[idx] = h[s];
    }
}

__global__ __launch_bounds__(256)
void scan_chunk_combine(const float* __restrict__ P, const float* __restrict__ Q,
                        float* __restrict__ HS)
{
    int n = blockIdx.x * 256 + threadIdx.x;        // 65536
    int i = n & (DI - 1);
    int s = (n >> 10) & (DS - 1);
    int b = n >> 14;
    float h = 0.f;
    for (int c = 0; c < NC; ++c) {
        size_t idx = ((size_t)((b * NC + c) * DS + s)) * DI + i;
        HS[idx] = h;
        h = fmaf(P[idx], h, Q[idx]);
    }
}

__global__ __launch_bounds__(64)
void scan_chunk_apply(const bf16* __restrict__ xcb, const float* __restrict__ dlx,
                      const bf16* __restrict__ xrb, const float* __restrict__ A_log,
                      const float* __restrict__ Dskip, const float* __restrict__ HS,
                      bf16* __restrict__ ybf)
{
    const int b = blockIdx.z, c = blockIdx.y;
    const int i = blockIdx.x * 64 + threadIdx.x;

    float a[DS];
    #pragma unroll
    for (int s = 0; s < DS; ++s) a[s] = A_log[s];
    float h[DS];
    #pragma unroll
    for (int s = 0; s < DS; ++s)
        h[s] = HS[((size_t)((b * NC + c) * DS + s)) * DI + i];
    const float dsk = Dskip[i];

    const int row0 = b * LL + c * CT;
    for (int t = 0; t < CT; ++t) {
        const size_t row = row0 + t;
        float d = dlx[row * NDTX + i];
        float u = b2f(xcb[row * DI + i]);
        const float* sp = dlx + row * NDTX + 1024;
        float y = 0.f;
        #pragma unroll
        for (int s = 0; s < DS; ++s) {
            float e = fminf(fmaxf(d * a[s], -5.f), 5.f);
            float dA = __expf(e);
            h[s] = fmaf(dA, h[s], (d * sp[s]) * u);
            y = fmaf(h[s], sp[DS + s], y);
        }
        float res = b2f(xrb[row * 2048 + DI + i]);
        float g = res / (1.f + __expf(-res));
        ybf[row * DI + i] = __float2bfloat16((y + u * dsk) * g);
    }
}

// ---------------------------------------------------------------------------
// r = outp + clip(x_raw); LayerNorm over 512; store per detected dtype.
// ---------------------------------------------------------------------------
__global__ __launch_bounds__(256)
void ln_kernel(const float* __restrict__ outp, const void* __restrict__ xsrc,
               const float* __restrict__ gamma, const float* __restrict__ beta,
               void* __restrict__ out, const int* __restrict__ flag)
{
    const int row = blockIdx.x;
    const int tid = threadIdx.x;
    const int isbf = *flag;

    float r[2];
    float sum = 0.f, ss = 0.f;
    #pragma unroll
    for (int q = 0; q < 2; ++q) {
        int j = tid + q * 256;
        float xv = load_flag(xsrc, row * DM + j, isbf);
        xv = fminf(fmaxf(xv, -10.f), 10.f);
        float v = outp[(size_t)row * DM + j] + xv;
        r[q] = v;
        sum += v;
        ss = fmaf(v, v, ss);
    }
    #pragma unroll
    for (int off = 32; off >= 1; off >>= 1) {
        sum += __shfl_down(sum, off);
        ss  += __shfl_down(ss, off);
    }
    __shared__ float s1[4], s2[4];
    __shared__ float stats[2];
    int wid = tid >> 6, lane = tid & 63;
    if (lane == 0) { s1[wid] = sum; s2[wid] = ss; }
    __syncthreads();
    if (tid == 0) {
        float S = s1[0] + s1[1] + s1[2] + s1[3];
        float Qq = s2[0] + s2[1] + s2[2] + s2[3];
        float mean = S / DM;
        float var = Qq / DM - mean * mean;
        stats[0] = mean;
        stats[1] = rsqrtf(var + 1e-5f);
    }
    __syncthreads();
    float mean = stats[0], rstd = stats[1];
    #pragma unroll
    for (int q = 0; q < 2; ++q) {
        int j = tid + q * 256;
        float v = (r[q] - mean) * rstd * gamma[j] + beta[j];
        size_t o = (size_t)row * DM + j;
        if (isbf) ((bf16*)out)[o] = __float2bfloat16(v);
        else      ((float*)out)[o] = v;
    }
}

// ---------------------------------------------------------------------------
extern "C" void kernel_launch(void* const* d_in, const int* in_sizes, int n_in,
                              void* d_out, int out_size, void* d_ws, size_t ws_size,
                              hipStream_t stream)
{
    float* W = (float*)d_ws;
    float* dlx  = W;                       // 4096x1152 fp32 (delta|ssm)
    float* Pbuf = dlx  + 4718592;          // 4x64x16x1024 = 4194304
    float* Qbuf = Pbuf + 4194304;
    float* HS   = Qbuf + 4194304;
    float* ccw  = HS   + 4194304;          // conv_w 4096
    float* ccb  = ccw  + 4096;             // conv_b 1024
    float* cAlg = ccb  + 1024;             // A_log 16
    float* cDsk = cAlg + 16;               // D_skip 1024
    float* cgam = cDsk + 1024;             // gamma 512
    float* cbet = cgam + 512;              // beta 512
    float* bdtx = cbet + 512;              // bias_dtx 1152
    int*   flag = (int*)(bdtx + 1152);
    bf16*  xbf  = (bf16*)(flag + 16);      // 4096x512   clipped x bf16
    bf16*  xrb  = xbf  + 2097152;          // 4096x2048  x_and_res bf16
    bf16*  xcb  = xrb  + 8388608;          // 4096x1024  conv+silu bf16
    bf16*  ybf  = xcb  + 4194304;          // 4096x1024  gated y bf16
    bf16*  WtIn = ybf  + 4194304;          // 2048x512
    bf16*  WtDtx= WtIn + 1048576;          // 1152x1024
    bf16*  WtOut= WtDtx+ 1179648;          // 512x1024
    float* outp = Pbuf;                    // 4096x512 fp32 (aliases dead Pbuf)

    // 0) dtype detection (probe W_dt = d_in[5])
    detect_dtype<<<1, 256, 0, stream>>>((const ushort_t*)d_in[5], flag);

    // 1) small params + dtx bias + WtDtx pad-zero (one kernel)
    prep_small<<<(106640 + 255) / 256, 256, 0, stream>>>(
        d_in[2], d_in[3], d_in[7], d_in[8], d_in[10], d_in[11], d_in[6],
        ccw, ccb, cAlg, cDsk, cgam, cbet, bdtx, WtDtx + 1056 * 1024, flag);

    // 2) x -> clipped bf16
    pack_x<<<ROWS * DM / 256, 256, 0, stream>>>(d_in[0], xbf, flag);

    // 3) all weight transposes (LDS-tiled, one kernel)
    transpose_all<<<2592, 256, 0, stream>>>(
        d_in[1], d_in[5], d_in[4], d_in[9], WtIn, WtDtx, WtOut, flag);

    // 4) x_and_res = clip(x) @ W_in        [4096,2048] bf16 out
    gemm_mfma<128, true><<<dim3(2048 / 128, ROWS / 128), 256, 0, stream>>>(
        xbf, WtIn, nullptr, xrb, ROWS, 2048, 512);

    // 5) depthwise causal conv + SiLU -> bf16 xc
    conv_silu<<<ROWS * DI / 256, 256, 0, stream>>>(xrb, ccw, ccb, xcb);

    // 6) [delta | ssm] = xc @ [W_dt | W_x] (+[b_dt|0])   [4096,1152] fp32
    gemm_mfma<64, false><<<dim3(NDTX / 128, ROWS / 64), 256, 0, stream>>>(
        xcb, WtDtx, bdtx, dlx, ROWS, NDTX, DI);

    // 7) chunked selective scan -> gated bf16 y
    scan_chunk_summary<<<dim3(DI / 64, NC, BB), 64, 0, stream>>>(
        xcb, dlx, cAlg, Pbuf, Qbuf);
    scan_chunk_combine<<<BB * DS * DI / 256, 256, 0, stream>>>(Pbuf, Qbuf, HS);
    scan_chunk_apply<<<dim3(DI / 64, NC, BB), 64, 0, stream>>>(
        xcb, dlx, xrb, cAlg, cDsk, HS, ybf);

    // 8) out_pre = y @ W_out               [4096,512] fp32 (aliases Pbuf)
    gemm_mfma<64, false><<<dim3(DM / 128, ROWS / 64), 256, 0, stream>>>(
        ybf, WtOut, nullptr, outp, ROWS, DM, DI);

    // 9) LayerNorm(out_pre + clip(x)) -> out (dtype per flag)
    ln_kernel<<<ROWS, 256, 0, stream>>>(outp, d_in[0], cgam, cbet, d_out, flag);
}

// Round 6
// 233.986 us; speedup vs baseline: 5.4854x; 1.0404x over previous
//
#include <hip/hip_runtime.h>
#include <hip/hip_bf16.h>

typedef __hip_bfloat16 bf16;
typedef unsigned short ushort_t;
typedef unsigned int uint_t;
typedef __attribute__((ext_vector_type(8))) __bf16 bf16x8;
typedef __attribute__((ext_vector_type(4))) float f32x4;

#define BB 4
#define LL 1024
#define DM 512
#define DS 16
#define DI 1024
#define ROWS 4096
#define NC 64
#define CT 16
#define NDTX 1152   // padded N for the fused [delta | ssm] GEMM (9*128)

__device__ __forceinline__ float b2f(bf16 v) { return __bfloat162float(v); }

__device__ __forceinline__ float load_flag(const void* src, int i, int isbf)
{
    return isbf ? b2f(((const bf16*)src)[i]) : ((const float*)src)[i];
}

__device__ __forceinline__ ushort_t f2b_bits(float v)
{
    bf16 t = __float2bfloat16(v);
    return *(ushort_t*)&t;
}

// Per-block dtype detection: sample 256 16-bit words of W_dt (scale 0.02).
// bf16 data -> 0 words with bf16-exponent >= 127; fp32 data -> ~64 of 256.
__device__ __forceinline__ int detect_local(const ushort_t* wdt)
{
    __shared__ int bad;
    if (threadIdx.x == 0) bad = 0;
    __syncthreads();
    ushort_t u = wdt[threadIdx.x];
    if (((u >> 7) & 0xFF) >= 127) atomicAdd(&bad, 1);
    __syncthreads();
    return (bad <= 8) ? 1 : 0;   // 1 = bf16 inputs
}

// ---------------------------------------------------------------------------
// ALL prep in one launch. Block ranges:
//   [0,2048):      pack_x  (x -> clipped bf16, 4 elems/thread, 16B/8B vector IO)
//   [2048,4640):   weight transposes (LDS 32x32 tile)
//   [4640,5057):   small params + dtx bias + WtDtx pad-zero
// ---------------------------------------------------------------------------
__global__ __launch_bounds__(256)
void prep_all(const void* x, const void* Win, const void* Wdt, const void* Wx,
              const void* Wout, const void* cw, const void* cb, const void* Alog,
              const void* Dsk, const void* gam, const void* bet, const void* bdt,
              bf16* __restrict__ xbf, bf16* __restrict__ WtIn,
              bf16* __restrict__ WtDtx, bf16* __restrict__ WtOut,
              float* __restrict__ ccw, float* __restrict__ ccb,
              float* __restrict__ cAlg, float* __restrict__ cDsk,
              float* __restrict__ cgam, float* __restrict__ cbet,
              float* __restrict__ bdtx)
{
    const int isbf = detect_local((const ushort_t*)Wdt);
    int blk = blockIdx.x;

    if (blk < 2048) {
        // ---- pack_x: 2048*256*4 = 2,097,152 elements
        int idx = blk * 256 + threadIdx.x;
        float v[4];
        if (isbf) {
            uint2 raw = ((const uint2*)x)[idx];
            v[0] = __uint_as_float(raw.x << 16);
            v[1] = __uint_as_float(raw.x & 0xFFFF0000u);
            v[2] = __uint_as_float(raw.y << 16);
            v[3] = __uint_as_float(raw.y & 0xFFFF0000u);
        } else {
            float4 raw = ((const float4*)x)[idx];
            v[0] = raw.x; v[1] = raw.y; v[2] = raw.z; v[3] = raw.w;
        }
        uint_t b0, b1;
        b0 = f2b_bits(fminf(fmaxf(v[0], -10.f), 10.f))
           | ((uint_t)f2b_bits(fminf(fmaxf(v[1], -10.f), 10.f)) << 16);
        b1 = f2b_bits(fminf(fmaxf(v[2], -10.f), 10.f))
           | ((uint_t)f2b_bits(fminf(fmaxf(v[3], -10.f), 10.f)) << 16);
        uint2 ow; ow.x = b0; ow.y = b1;
        ((uint2*)xbf)[idx] = ow;
    } else if (blk < 4640) {
        // ---- transposes: src[K][Nsrc] -> dst[Nsrc][K] bf16
        int tb = blk - 2048;
        const void* src; bf16* dst; int K, Nsrc, tpr;
        if (tb < 1024)      { src = Win;  dst = WtIn;               K = 512;  Nsrc = 2048; tpr = 64; }
        else if (tb < 2048) { tb -= 1024; src = Wdt;  dst = WtDtx;  K = 1024; Nsrc = 1024; tpr = 32; }
        else if (tb < 2080) { tb -= 2048; src = Wx;   dst = WtDtx + 1024 * 1024; K = 1024; Nsrc = 32; tpr = 1; }
        else                { tb -= 2080; src = Wout; dst = WtOut;  K = 1024; Nsrc = 512;  tpr = 16; }
        int k0 = (tb / tpr) * 32, n0 = (tb % tpr) * 32;

        __shared__ float tile[32][33];
        int tx = threadIdx.x & 31, ty = threadIdx.x >> 5;
        #pragma unroll
        for (int j = 0; j < 4; ++j)
            tile[ty + 8 * j][tx] = load_flag(src, (k0 + ty + 8 * j) * Nsrc + n0 + tx, isbf);
        __syncthreads();
        #pragma unroll
        for (int j = 0; j < 4; ++j)
            dst[(size_t)(n0 + ty + 8 * j) * K + k0 + tx] = __float2bfloat16(tile[tx][ty + 8 * j]);
    } else {
        // ---- small params (ranges as documented)
        int i = (blk - 4640) * 256 + threadIdx.x;
        if (i < 4096)        ccw[i] = load_flag(cw, i, isbf);
        else if (i < 5120)   ccb[i - 4096] = load_flag(cb, i - 4096, isbf);
        else if (i < 5136)   cAlg[i - 5120] = load_flag(Alog, i - 5120, isbf);
        else if (i < 6160)   cDsk[i - 5136] = load_flag(Dsk, i - 5136, isbf);
        else if (i < 6672)   cgam[i - 6160] = load_flag(gam, i - 6160, isbf);
        else if (i < 7184)   cbet[i - 6672] = load_flag(bet, i - 6672, isbf);
        else if (i < 8336) {
            int j = i - 7184;
            bdtx[j] = (j < DI) ? load_flag(bdt, j, isbf) : 0.f;
        } else if (i < 106640) {
            (WtDtx + 1056 * 1024)[i - 8336] = __float2bfloat16(0.f);
        }
    }
}

// ---------------------------------------------------------------------------
// MFMA bf16 GEMM: C[M][N] = A[M][K] * Bt[N][K]^T (+bias).
// TM x TN tile, 4 waves (2x2), 16x16x32 frags, BK=32,
// global_load_lds width-16 staging with XOR k-chunk swizzle.
// ---------------------------------------------------------------------------
__device__ __forceinline__ void gload16(const bf16* g, ushort_t* l)
{
    __builtin_amdgcn_global_load_lds(
        (const __attribute__((address_space(1))) void*)g,
        (__attribute__((address_space(3))) void*)l, 16, 0, 0);
}

template <int TM, int TN, bool OBF>
__global__ __launch_bounds__(256)
void gemm_mfma(const bf16* __restrict__ A, const bf16* __restrict__ Bt,
               const float* __restrict__ bias, void* __restrict__ Cv,
               int M, int N, int K)
{
    constexpr int MI = TM / 32, NJ = TN / 32;
    constexpr int NLD = (TM + TN) / 64;       // 16B staging loads per thread
    __shared__ ushort_t As[TM * 32];
    __shared__ ushort_t Bs[TN * 32];

    const int tid = threadIdx.x;
    const int lane = tid & 63;
    const int w = tid >> 6;
    const int wr = w >> 1, wc = w & 1;
    const int m0 = blockIdx.y * TM;
    const int n0 = blockIdx.x * TN;

    // staging map: virtual 16B block p; row = p>>2; slot p&3 holds k-chunk ((p&3)-row)&3
    const bf16* gptr[NLD];
    ushort_t* lbase[NLD];
    #pragma unroll
    for (int q = 0; q < NLD; ++q) {
        int p = q * 256 + tid;
        if (q * 256 < TM * 4) {                       // A-part (uniform per q)
            int row = p >> 2, kc = ((p & 3) - row) & 3;
            gptr[q] = A + (size_t)(m0 + row) * K + kc * 8;
            lbase[q] = &As[(q * 256 + w * 64) * 8];
        } else {
            int pb = p - TM * 4;
            int row = pb >> 2, kc = ((pb & 3) - row) & 3;
            gptr[q] = Bt + (size_t)(n0 + row) * K + kc * 8;
            lbase[q] = &Bs[(q * 256 + w * 64 - TM * 4) * 8];
        }
    }

    f32x4 acc[MI][NJ];
    #pragma unroll
    for (int i = 0; i < MI; ++i)
        #pragma unroll
        for (int j = 0; j < NJ; ++j)
            acc[i][j] = (f32x4){0.f, 0.f, 0.f, 0.f};

    const int ko = lane >> 4;
    const int ml = lane & 15;

    for (int k0 = 0; k0 < K; k0 += 32) {
        #pragma unroll
        for (int q = 0; q < NLD; ++q)
            gload16(gptr[q] + k0, lbase[q]);
        __syncthreads();

        bf16x8 af[MI], bfr[NJ];
        #pragma unroll
        for (int i = 0; i < MI; ++i) {
            int m = wr * (TM / 2) + i * 16 + ml;
            af[i] = *(const bf16x8*)&As[(m * 4 + ((ko + m) & 3)) * 8];
        }
        #pragma unroll
        for (int j = 0; j < NJ; ++j) {
            int n = wc * (TN / 2) + j * 16 + ml;
            bfr[j] = *(const bf16x8*)&Bs[(n * 4 + ((ko + n) & 3)) * 8];
        }
        #pragma unroll
        for (int i = 0; i < MI; ++i)
            #pragma unroll
            for (int j = 0; j < NJ; ++j)
                acc[i][j] = __builtin_amdgcn_mfma_f32_16x16x32_bf16(
                    af[i], bfr[j], acc[i][j], 0, 0, 0);
        __syncthreads();
    }

    // C/D layout: col = lane&15, row = (lane>>4)*4 + reg
    const int rq = lane >> 4;
    #pragma unroll
    for (int j = 0; j < NJ; ++j) {
        int n = n0 + wc * (TN / 2) + j * 16 + ml;
        float bv = bias ? bias[n] : 0.f;
        #pragma unroll
        for (int i = 0; i < MI; ++i) {
            int mb = m0 + wr * (TM / 2) + i * 16 + rq * 4;
            #pragma unroll
            for (int r = 0; r < 4; ++r) {
                float v = acc[i][j][r] + bv;
                if (OBF) ((bf16*)Cv)[(size_t)(mb + r) * N + n] = __float2bfloat16(v);
                else     ((float*)Cv)[(size_t)(mb + r) * N + n] = v;
            }
        }
    }
}

// ---------------------------------------------------------------------------
// Depthwise causal conv (width 4) + SiLU. xrb bf16 [ROWS][2048]; xp = cols<DI.
// ---------------------------------------------------------------------------
__global__ __launch_bounds__(256)
void conv_silu(const bf16* __restrict__ xrb, const float* __restrict__ cw,
               const float* __restrict__ cb, bf16* __restrict__ xcb)
{
    int idx = blockIdx.x * 256 + threadIdx.x;
    int i = idx & (DI - 1);
    int row = idx >> 10;
    int t = row & (LL - 1);

    float w0 = cw[i * 4 + 0];
    float w1 = cw[i * 4 + 1];
    float w2 = cw[i * 4 + 2];
    float w3 = cw[i * 4 + 3];

    float acc = cb[i];
    const bf16* base = xrb + (size_t)row * 2048 + i;
    if (t >= 3) acc = fmaf(b2f(base[-3 * 2048]), w0, acc);
    if (t >= 2) acc = fmaf(b2f(base[-2 * 2048]), w1, acc);
    if (t >= 1) acc = fmaf(b2f(base[-1 * 2048]), w2, acc);
    acc = fmaf(b2f(base[0]), w3, acc);

    xcb[idx] = __float2bfloat16(acc / (1.f + __expf(-acc)));
}

// ---------------------------------------------------------------------------
// Chunked selective scan (3 passes), all streams bf16, fp32 arithmetic.
// delta at dlx[row*NDTX+i]; ssm (B|C) at dlx[row*NDTX+1024+s] (wave-uniform).
// ---------------------------------------------------------------------------
__global__ __launch_bounds__(64)
void scan_chunk_summary(const bf16* __restrict__ xcb, const bf16* __restrict__ dlx,
                        const float* __restrict__ A_log,
                        bf16* __restrict__ P, bf16* __restrict__ Q)
{
    const int b = blockIdx.z, c = blockIdx.y;
    const int i = blockIdx.x * 64 + threadIdx.x;

    float a[DS];
    #pragma unroll
    for (int s = 0; s < DS; ++s) a[s] = A_log[s];
    float h[DS] = {};
    float p[DS];
    #pragma unroll
    for (int s = 0; s < DS; ++s) p[s] = 1.f;

    const int row0 = b * LL + c * CT;
    for (int t = 0; t < CT; ++t) {
        const size_t row = row0 + t;
        float d = b2f(dlx[row * NDTX + i]);
        float u = b2f(xcb[row * DI + i]);
        const bf16* sp = dlx + row * NDTX + 1024;
        #pragma unroll
        for (int s = 0; s < DS; ++s) {
            float e = fminf(fmaxf(d * a[s], -5.f), 5.f);
            float dA = __expf(e);
            h[s] = fmaf(dA, h[s], (d * b2f(sp[s])) * u);
            p[s] *= dA;
        }
    }
    #pragma unroll
    for (int s = 0; s < DS; ++s) {
        size_t idx = ((size_t)((b * NC + c) * DS + s)) * DI + i;
        P[idx] = __float2bfloat16(p[s]);
        Q[idx] = __float2bfloat16(h[s]);
    }
}

__global__ __launch_bounds__(256)
void scan_chunk_combine(const bf16* __restrict__ P, const bf16* __restrict__ Q,
                        bf16* __restrict__ HS)
{
    int n = blockIdx.x * 256 + threadIdx.x;        // 65536
    int i = n & (DI - 1);
    int s = (n >> 10) & (DS - 1);
    int b = n >> 14;
    float h = 0.f;
    for (int c = 0; c < NC; ++c) {
        size_t idx = ((size_t)((b * NC + c) * DS + s)) * DI + i;
        HS[idx] = __float2bfloat16(h);
        h = fmaf(b2f(P[idx]), h, b2f(Q[idx]));
    }
}

__global__ __launch_bounds__(64)
void scan_chunk_apply(const bf16* __restrict__ xcb, const bf16* __restrict__ dlx,
                      const bf16* __restrict__ xrb, const float* __restrict__ A_log,
                      const float* __restrict__ Dskip, const bf16* __restrict__ HS,
                      bf16* __restrict__ ybf)
{
    const int b = blockIdx.z, c = blockIdx.y;
    const int i = blockIdx.x * 64 + threadIdx.x;

    float a[DS];
    #pragma unroll
    for (int s = 0; s < DS; ++s) a[s] = A_log[s];
    float h[DS];
    #pragma unroll
    for (int s = 0; s < DS; ++s)
        h[s] = b2f(HS[((size_t)((b * NC + c) * DS + s)) * DI + i]);
    const float dsk = Dskip[i];

    const int row0 = b * LL + c * CT;
    for (int t = 0; t < CT; ++t) {
        const size_t row = row0 + t;
        float d = b2f(dlx[row * NDTX + i]);
        float u = b2f(xcb[row * DI + i]);
        const bf16* sp = dlx + row * NDTX + 1024;
        float y = 0.f;
        #pragma unroll
        for (int s = 0; s < DS; ++s) {
            float e = fminf(fmaxf(d * a[s], -5.f), 5.f);
            float dA = __expf(e);
            h[s] = fmaf(dA, h[s], (d * b2f(sp[s])) * u);
            y = fmaf(h[s], b2f(sp[DS + s]), y);
        }
        float res = b2f(xrb[row * 2048 + DI + i]);
        float g = res / (1.f + __expf(-res));
        ybf[row * DI + i] = __float2bfloat16((y + u * dsk) * g);
    }
}

// ---------------------------------------------------------------------------
// r = outp + clip(x_raw); LayerNorm over 512; dtype detected locally.
// ---------------------------------------------------------------------------
__global__ __launch_bounds__(256)
void ln_kernel(const float* __restrict__ outp, const void* __restrict__ xsrc,
               const void* __restrict__ wdt_probe,
               const float* __restrict__ gamma, const float* __restrict__ beta,
               void* __restrict__ out)
{
    const int isbf = detect_local((const ushort_t*)wdt_probe);
    const int row = blockIdx.x;
    const int tid = threadIdx.x;

    float r[2];
    float sum = 0.f, ss = 0.f;
    #pragma unroll
    for (int q = 0; q < 2; ++q) {
        int j = tid + q * 256;
        float xv = load_flag(xsrc, row * DM + j, isbf);
        xv = fminf(fmaxf(xv, -10.f), 10.f);
        float v = outp[(size_t)row * DM + j] + xv;
        r[q] = v;
        sum += v;
        ss = fmaf(v, v, ss);
    }
    #pragma unroll
    for (int off = 32; off >= 1; off >>= 1) {
        sum += __shfl_down(sum, off);
        ss  += __shfl_down(ss, off);
    }
    __shared__ float s1[4], s2[4];
    __shared__ float stats[2];
    int wid = tid >> 6, lane = tid & 63;
    if (lane == 0) { s1[wid] = sum; s2[wid] = ss; }
    __syncthreads();
    if (tid == 0) {
        float S = s1[0] + s1[1] + s1[2] + s1[3];
        float Qq = s2[0] + s2[1] + s2[2] + s2[3];
        float mean = S / DM;
        float var = Qq / DM - mean * mean;
        stats[0] = mean;
        stats[1] = rsqrtf(var + 1e-5f);
    }
    __syncthreads();
    float mean = stats[0], rstd = stats[1];
    #pragma unroll
    for (int q = 0; q < 2; ++q) {
        int j = tid + q * 256;
        float v = (r[q] - mean) * rstd * gamma[j] + beta[j];
        size_t o = (size_t)row * DM + j;
        if (isbf) ((bf16*)out)[o] = __float2bfloat16(v);
        else      ((float*)out)[o] = v;
    }
}

// ---------------------------------------------------------------------------
extern "C" void kernel_launch(void* const* d_in, const int* in_sizes, int n_in,
                              void* d_out, int out_size, void* d_ws, size_t ws_size,
                              hipStream_t stream)
{
    float* W = (float*)d_ws;
    // fp32 section (2,105,488 floats -> bf16 section starts 16B-aligned)
    float* ccw  = W;                       // 4096
    float* ccb  = ccw  + 4096;             // 1024
    float* cAlg = ccb  + 1024;             // 16
    float* cDsk = cAlg + 16;               // 1024
    float* cgam = cDsk + 1024;             // 512
    float* cbet = cgam + 512;              // 512
    float* bdtx = cbet + 512;              // 1152
    float* outp = bdtx + 1152;             // 4096x512 fp32
    // bf16 section
    bf16*  xbf  = (bf16*)(outp + 2097152); // 4096x512
    bf16*  xrb  = xbf  + 2097152;          // 4096x2048
    bf16*  xcb  = xrb  + 8388608;          // 4096x1024
    bf16*  ybf  = xcb  + 4194304;          // 4096x1024
    bf16*  dlx  = ybf  + 4194304;          // 4096x1152 (delta|B|C)
    bf16*  Pbuf = dlx  + 4718592;          // 4x64x16x1024
    bf16*  Qbuf = Pbuf + 4194304;
    bf16*  HS   = Qbuf + 4194304;
    bf16*  WtIn = HS   + 4194304;          // 2048x512
    bf16*  WtDtx= WtIn + 1048576;          // 1152x1024
    bf16*  WtOut= WtDtx+ 1179648;          // 512x1024

    // 1) all prep (dtype detect per block, pack x, transposes, small params)
    prep_all<<<5057, 256, 0, stream>>>(
        d_in[0], d_in[1], d_in[5], d_in[4], d_in[9], d_in[2], d_in[3],
        d_in[7], d_in[8], d_in[10], d_in[11], d_in[6],
        xbf, WtIn, WtDtx, WtOut, ccw, ccb, cAlg, cDsk, cgam, cbet, bdtx);

    // 2) x_and_res = clip(x) @ W_in        [4096,2048] bf16, 1024 blocks
    gemm_mfma<64, 128, true><<<dim3(2048 / 128, ROWS / 64), 256, 0, stream>>>(
        xbf, WtIn, nullptr, xrb, ROWS, 2048, 512);

    // 3) depthwise causal conv + SiLU -> bf16 xc
    conv_silu<<<ROWS * DI / 256, 256, 0, stream>>>(xrb, ccw, ccb, xcb);

    // 4) [delta | ssm] = xc @ [W_dt | W_x] (+[b_dt|0])   [4096,1152] bf16
    gemm_mfma<64, 128, true><<<dim3(NDTX / 128, ROWS / 64), 256, 0, stream>>>(
        xcb, WtDtx, bdtx, dlx, ROWS, NDTX, DI);

    // 5) chunked selective scan -> gated bf16 y
    scan_chunk_summary<<<dim3(DI / 64, NC, BB), 64, 0, stream>>>(
        xcb, dlx, cAlg, Pbuf, Qbuf);
    scan_chunk_combine<<<BB * DS * DI / 256, 256, 0, stream>>>(Pbuf, Qbuf, HS);
    scan_chunk_apply<<<dim3(DI / 64, NC, BB), 64, 0, stream>>>(
        xcb, dlx, xrb, cAlg, cDsk, HS, ybf);

    // 6) out_pre = y @ W_out               [4096,512] fp32, 512 blocks
    gemm_mfma<64, 64, false><<<dim3(DM / 64, ROWS / 64), 256, 0, stream>>>(
        ybf, WtOut, nullptr, outp, ROWS, DM, DI);

    // 7) LayerNorm(out_pre + clip(x)) -> out (dtype detected locally)
    ln_kernel<<<ROWS, 256, 0, stream>>>(outp, d_in[0], d_in[5], cgam, cbet, d_out);
}

// Round 7
// 226.358 us; speedup vs baseline: 5.6702x; 1.0337x over previous
//
#include <hip/hip_runtime.h>
#include <hip/hip_bf16.h>

typedef __hip_bfloat16 bf16;
typedef unsigned short ushort_t;
typedef unsigned int uint_t;
typedef __attribute__((ext_vector_type(8))) __bf16 bf16x8;
typedef __attribute__((ext_vector_type(4))) float f32x4;

#define BB 4
#define LL 1024
#define DM 512
#define DS 16
#define DI 1024
#define ROWS 4096
#define NC 64
#define CT 16
#define NDTX 1152   // padded N for the fused [delta | ssm] GEMM (9*128)

__device__ __forceinline__ float b2f(bf16 v) { return __bfloat162float(v); }

__device__ __forceinline__ float load_flag(const void* src, int i, int isbf)
{
    return isbf ? b2f(((const bf16*)src)[i]) : ((const float*)src)[i];
}

__device__ __forceinline__ ushort_t f2b_bits(float v)
{
    bf16 t = __float2bfloat16(v);
    return *(ushort_t*)&t;
}

__device__ __forceinline__ float bits2f(ushort_t u)
{
    uint_t w = ((uint_t)u) << 16;
    return __uint_as_float(w);
}

// Per-block dtype detection: sample 256 16-bit words of W_dt (scale 0.02).
// bf16 data -> 0 words with bf16-exponent >= 127; fp32 data -> ~64 of 256.
__device__ __forceinline__ int detect_local(const ushort_t* wdt)
{
    __shared__ int bad;
    if (threadIdx.x == 0) bad = 0;
    __syncthreads();
    ushort_t u = wdt[threadIdx.x & 255];
    if (((u >> 7) & 0xFF) >= 127) atomicAdd(&bad, 1);
    __syncthreads();
    return (bad <= 8) ? 1 : 0;   // 1 = bf16 inputs
}

// ---------------------------------------------------------------------------
// ALL prep in one launch. Block ranges:
//   [0,2048):      pack_x  (x -> clipped bf16, 4 elems/thread)
//   [2048,4640):   weight transposes (LDS 32x32 tile)
//   [4640,5057):   small params + dtx bias + WtDtx pad-zero
// ---------------------------------------------------------------------------
__global__ __launch_bounds__(256)
void prep_all(const void* x, const void* Win, const void* Wdt, const void* Wx,
              const void* Wout, const void* cw, const void* cb, const void* Alog,
              const void* Dsk, const void* gam, const void* bet, const void* bdt,
              bf16* __restrict__ xbf, bf16* __restrict__ WtIn,
              bf16* __restrict__ WtDtx, bf16* __restrict__ WtOut,
              float* __restrict__ ccw, float* __restrict__ ccb,
              float* __restrict__ cAlg, float* __restrict__ cDsk,
              float* __restrict__ cgam, float* __restrict__ cbet,
              float* __restrict__ bdtx)
{
    const int isbf = detect_local((const ushort_t*)Wdt);
    int blk = blockIdx.x;

    if (blk < 2048) {
        int idx = blk * 256 + threadIdx.x;
        float v[4];
        if (isbf) {
            uint2 raw = ((const uint2*)x)[idx];
            v[0] = __uint_as_float(raw.x << 16);
            v[1] = __uint_as_float(raw.x & 0xFFFF0000u);
            v[2] = __uint_as_float(raw.y << 16);
            v[3] = __uint_as_float(raw.y & 0xFFFF0000u);
        } else {
            float4 raw = ((const float4*)x)[idx];
            v[0] = raw.x; v[1] = raw.y; v[2] = raw.z; v[3] = raw.w;
        }
        uint_t b0, b1;
        b0 = f2b_bits(fminf(fmaxf(v[0], -10.f), 10.f))
           | ((uint_t)f2b_bits(fminf(fmaxf(v[1], -10.f), 10.f)) << 16);
        b1 = f2b_bits(fminf(fmaxf(v[2], -10.f), 10.f))
           | ((uint_t)f2b_bits(fminf(fmaxf(v[3], -10.f), 10.f)) << 16);
        uint2 ow; ow.x = b0; ow.y = b1;
        ((uint2*)xbf)[idx] = ow;
    } else if (blk < 4640) {
        int tb = blk - 2048;
        const void* src; bf16* dst; int K, Nsrc, tpr;
        if (tb < 1024)      { src = Win;  dst = WtIn;               K = 512;  Nsrc = 2048; tpr = 64; }
        else if (tb < 2048) { tb -= 1024; src = Wdt;  dst = WtDtx;  K = 1024; Nsrc = 1024; tpr = 32; }
        else if (tb < 2080) { tb -= 2048; src = Wx;   dst = WtDtx + 1024 * 1024; K = 1024; Nsrc = 32; tpr = 1; }
        else                { tb -= 2080; src = Wout; dst = WtOut;  K = 1024; Nsrc = 512;  tpr = 16; }
        int k0 = (tb / tpr) * 32, n0 = (tb % tpr) * 32;

        __shared__ float tile[32][33];
        int tx = threadIdx.x & 31, ty = threadIdx.x >> 5;
        #pragma unroll
        for (int j = 0; j < 4; ++j)
            tile[ty + 8 * j][tx] = load_flag(src, (k0 + ty + 8 * j) * Nsrc + n0 + tx, isbf);
        __syncthreads();
        #pragma unroll
        for (int j = 0; j < 4; ++j)
            dst[(size_t)(n0 + ty + 8 * j) * K + k0 + tx] = __float2bfloat16(tile[tx][ty + 8 * j]);
    } else {
        int i = (blk - 4640) * 256 + threadIdx.x;
        if (i < 4096)        ccw[i] = load_flag(cw, i, isbf);
        else if (i < 5120)   ccb[i - 4096] = load_flag(cb, i - 4096, isbf);
        else if (i < 5136)   cAlg[i - 5120] = load_flag(Alog, i - 5120, isbf);
        else if (i < 6160)   cDsk[i - 5136] = load_flag(Dsk, i - 5136, isbf);
        else if (i < 6672)   cgam[i - 6160] = load_flag(gam, i - 6160, isbf);
        else if (i < 7184)   cbet[i - 6672] = load_flag(bet, i - 6672, isbf);
        else if (i < 8336) {
            int j = i - 7184;
            bdtx[j] = (j < DI) ? load_flag(bdt, j, isbf) : 0.f;
        } else if (i < 106640) {
            (WtDtx + 1056 * 1024)[i - 8336] = __float2bfloat16(0.f);
        }
    }
}

// ---------------------------------------------------------------------------
// MFMA bf16 GEMM: C[M][N] = A[M][K] * Bt[N][K]^T (+bias).
// TM x TN tile, 4 waves (2x2), 16x16x32 frags, BK=64 (two 32-k halves per
// staging barrier), global_load_lds width-16 with XOR 8-chunk swizzle.
// ---------------------------------------------------------------------------
__device__ __forceinline__ void gload16(const bf16* g, ushort_t* l)
{
    __builtin_amdgcn_global_load_lds(
        (const __attribute__((address_space(1))) void*)g,
        (__attribute__((address_space(3))) void*)l, 16, 0, 0);
}

template <int TM, int TN, bool OBF>
__global__ __launch_bounds__(256)
void gemm_mfma(const bf16* __restrict__ A, const bf16* __restrict__ Bt,
               const float* __restrict__ bias, void* __restrict__ Cv,
               int M, int N, int K)
{
    constexpr int MI = TM / 32, NJ = TN / 32;
    constexpr int NQA = TM * 8 / 256;   // 16B staging loads per thread (A)
    constexpr int NQB = TN * 8 / 256;   // (B)
    __shared__ ushort_t As[TM * 64];
    __shared__ ushort_t Bs[TN * 64];

    const int tid = threadIdx.x;
    const int lane = tid & 63;
    const int w = tid >> 6;
    const int wr = w >> 1, wc = w & 1;
    const int m0 = blockIdx.y * TM;
    const int n0 = blockIdx.x * TN;

    // staging map: 16B block p; row = p>>3; slot p&7 holds k-chunk ((p&7)-row)&7
    const bf16* gA[NQA]; ushort_t* lA[NQA];
    #pragma unroll
    for (int q = 0; q < NQA; ++q) {
        int p = q * 256 + tid;
        int row = p >> 3, kc = ((p & 7) - row) & 7;
        gA[q] = A + (size_t)(m0 + row) * K + kc * 8;
        lA[q] = &As[(q * 256 + w * 64) * 8];
    }
    const bf16* gB[NQB]; ushort_t* lB[NQB];
    #pragma unroll
    for (int q = 0; q < NQB; ++q) {
        int p = q * 256 + tid;
        int row = p >> 3, kc = ((p & 7) - row) & 7;
        gB[q] = Bt + (size_t)(n0 + row) * K + kc * 8;
        lB[q] = &Bs[(q * 256 + w * 64) * 8];
    }

    f32x4 acc[MI][NJ];
    #pragma unroll
    for (int i = 0; i < MI; ++i)
        #pragma unroll
        for (int j = 0; j < NJ; ++j)
            acc[i][j] = (f32x4){0.f, 0.f, 0.f, 0.f};

    const int ko = lane >> 4;
    const int ml = lane & 15;

    for (int k0 = 0; k0 < K; k0 += 64) {
        #pragma unroll
        for (int q = 0; q < NQA; ++q) gload16(gA[q] + k0, lA[q]);
        #pragma unroll
        for (int q = 0; q < NQB; ++q) gload16(gB[q] + k0, lB[q]);
        __syncthreads();

        #pragma unroll
        for (int half = 0; half < 2; ++half) {
            bf16x8 af[MI], bfr[NJ];
            #pragma unroll
            for (int i = 0; i < MI; ++i) {
                int m = wr * (TM / 2) + i * 16 + ml;
                af[i] = *(const bf16x8*)&As[(m * 8 + ((half * 4 + ko + m) & 7)) * 8];
            }
            #pragma unroll
            for (int j = 0; j < NJ; ++j) {
                int n = wc * (TN / 2) + j * 16 + ml;
                bfr[j] = *(const bf16x8*)&Bs[(n * 8 + ((half * 4 + ko + n) & 7)) * 8];
            }
            #pragma unroll
            for (int i = 0; i < MI; ++i)
                #pragma unroll
                for (int j = 0; j < NJ; ++j)
                    acc[i][j] = __builtin_amdgcn_mfma_f32_16x16x32_bf16(
                        af[i], bfr[j], acc[i][j], 0, 0, 0);
        }
        __syncthreads();
    }

    // C/D layout: col = lane&15, row = (lane>>4)*4 + reg
    const int rq = lane >> 4;
    #pragma unroll
    for (int j = 0; j < NJ; ++j) {
        int n = n0 + wc * (TN / 2) + j * 16 + ml;
        float bv = bias ? bias[n] : 0.f;
        #pragma unroll
        for (int i = 0; i < MI; ++i) {
            int mb = m0 + wr * (TM / 2) + i * 16 + rq * 4;
            #pragma unroll
            for (int r = 0; r < 4; ++r) {
                float v = acc[i][j][r] + bv;
                if (OBF) ((bf16*)Cv)[(size_t)(mb + r) * N + n] = __float2bfloat16(v);
                else     ((float*)Cv)[(size_t)(mb + r) * N + n] = v;
            }
        }
    }
}

// ---------------------------------------------------------------------------
// Depthwise causal conv (width 4) + SiLU. xrb bf16 [ROWS][2048]; xp = cols<DI.
// ---------------------------------------------------------------------------
__global__ __launch_bounds__(256)
void conv_silu(const bf16* __restrict__ xrb, const float* __restrict__ cw,
               const float* __restrict__ cb, bf16* __restrict__ xcb)
{
    int idx = blockIdx.x * 256 + threadIdx.x;
    int i = idx & (DI - 1);
    int row = idx >> 10;
    int t = row & (LL - 1);

    float w0 = cw[i * 4 + 0];
    float w1 = cw[i * 4 + 1];
    float w2 = cw[i * 4 + 2];
    float w3 = cw[i * 4 + 3];

    float acc = cb[i];
    const bf16* base = xrb + (size_t)row * 2048 + i;
    if (t >= 3) acc = fmaf(b2f(base[-3 * 2048]), w0, acc);
    if (t >= 2) acc = fmaf(b2f(base[-2 * 2048]), w1, acc);
    if (t >= 1) acc = fmaf(b2f(base[-1 * 2048]), w2, acc);
    acc = fmaf(b2f(base[0]), w3, acc);

    xcb[idx] = __float2bfloat16(acc / (1.f + __expf(-acc)));
}

// ---------------------------------------------------------------------------
// FUSED chunked selective scan: summary + combine + apply in one kernel.
// Grid: 256 blocks = 4 batches x 64 channel-groups (16 channels each).
// Block: 1024 threads = 16 channels x 64 chunks of CT=16 steps.
// Pass A: per-thread chunk recurrence from h=0 (d,u cached in registers),
//         chunk P (prod dA) and Q (h_end) -> LDS (bf16).
// Combine: 256 threads (chl,s) serial over 64 chunks in LDS; P slot
//          overwritten with h_start.
// Pass C: rerun chunk from h_start, apply D-skip + silu(res) gate -> ybf.
// ---------------------------------------------------------------------------
__global__ __launch_bounds__(1024)
void scan_fused(const bf16* __restrict__ xcb, const bf16* __restrict__ dlx,
                const bf16* __restrict__ xrb, const float* __restrict__ A_log,
                const float* __restrict__ Dskip, bf16* __restrict__ ybf)
{
    __shared__ ushort_t lp[NC * 16 * DS];   // 32 KB
    __shared__ ushort_t lq[NC * 16 * DS];   // 32 KB

    const int b = blockIdx.x >> 6;
    const int ch0 = (blockIdx.x & 63) << 4;
    const int chl = threadIdx.x & 15;
    const int c = threadIdx.x >> 4;          // chunk 0..63
    const int i = ch0 + chl;

    float a[DS];
    #pragma unroll
    for (int s = 0; s < DS; ++s) a[s] = A_log[s];

    const int row0 = b * LL + c * CT;
    float d[CT], u[CT];
    float h[DS] = {};
    float p[DS];
    #pragma unroll
    for (int s = 0; s < DS; ++s) p[s] = 1.f;

    // ---- Pass A
    for (int t = 0; t < CT; ++t) {
        const size_t row = row0 + t;
        d[t] = b2f(dlx[row * NDTX + i]);
        u[t] = b2f(xcb[row * DI + i]);
        const bf16* sp = dlx + row * NDTX + 1024;
        #pragma unroll
        for (int s = 0; s < DS; ++s) {
            float e = fminf(fmaxf(d[t] * a[s], -5.f), 5.f);
            float dA = __expf(e);
            h[s] = fmaf(dA, h[s], (d[t] * b2f(sp[s])) * u[t]);
            p[s] *= dA;
        }
    }
    {
        const int off = (c * 16 + chl) * DS;
        #pragma unroll
        for (int s = 0; s < DS; ++s) {
            lp[off + s] = f2b_bits(p[s]);
            lq[off + s] = f2b_bits(h[s]);
        }
    }
    __syncthreads();

    // ---- Combine (threads 0..255): (chl, s) serial over chunks
    if (threadIdx.x < 256) {
        int cl = threadIdx.x & 15;
        int s = threadIdx.x >> 4;
        float hh = 0.f;
        for (int cc = 0; cc < NC; ++cc) {
            int off = (cc * 16 + cl) * DS + s;
            float pp = bits2f(lp[off]);
            float qq = bits2f(lq[off]);
            lp[off] = f2b_bits(hh);          // h at chunk start
            hh = fmaf(pp, hh, qq);
        }
    }
    __syncthreads();

    // ---- Pass C
    {
        const int off = (c * 16 + chl) * DS;
        #pragma unroll
        for (int s = 0; s < DS; ++s) h[s] = bits2f(lp[off + s]);
    }
    const float dsk = Dskip[i];
    for (int t = 0; t < CT; ++t) {
        const size_t row = row0 + t;
        const bf16* sp = dlx + row * NDTX + 1024;
        float y = 0.f;
        #pragma unroll
        for (int s = 0; s < DS; ++s) {
            float e = fminf(fmaxf(d[t] * a[s], -5.f), 5.f);
            float dA = __expf(e);
            h[s] = fmaf(dA, h[s], (d[t] * b2f(sp[s])) * u[t]);
            y = fmaf(h[s], b2f(sp[DS + s]), y);
        }
        float res = b2f(xrb[row * 2048 + DI + i]);
        float g = res / (1.f + __expf(-res));
        ybf[row * DI + i] = __float2bfloat16((y + u[t] * dsk) * g);
    }
}

// ---------------------------------------------------------------------------
// r = outp + clip(x_raw); LayerNorm over 512; dtype detected locally.
// ---------------------------------------------------------------------------
__global__ __launch_bounds__(256)
void ln_kernel(const float* __restrict__ outp, const void* __restrict__ xsrc,
               const void* __restrict__ wdt_probe,
               const float* __restrict__ gamma, const float* __restrict__ beta,
               void* __restrict__ out)
{
    const int isbf = detect_local((const ushort_t*)wdt_probe);
    const int row = blockIdx.x;
    const int tid = threadIdx.x;

    float r[2];
    float sum = 0.f, ss = 0.f;
    #pragma unroll
    for (int q = 0; q < 2; ++q) {
        int j = tid + q * 256;
        float xv = load_flag(xsrc, row * DM + j, isbf);
        xv = fminf(fmaxf(xv, -10.f), 10.f);
        float v = outp[(size_t)row * DM + j] + xv;
        r[q] = v;
        sum += v;
        ss = fmaf(v, v, ss);
    }
    #pragma unroll
    for (int off = 32; off >= 1; off >>= 1) {
        sum += __shfl_down(sum, off);
        ss  += __shfl_down(ss, off);
    }
    __shared__ float s1[4], s2[4];
    __shared__ float stats[2];
    int wid = tid >> 6, lane = tid & 63;
    if (lane == 0) { s1[wid] = sum; s2[wid] = ss; }
    __syncthreads();
    if (tid == 0) {
        float S = s1[0] + s1[1] + s1[2] + s1[3];
        float Qq = s2[0] + s2[1] + s2[2] + s2[3];
        float mean = S / DM;
        float var = Qq / DM - mean * mean;
        stats[0] = mean;
        stats[1] = rsqrtf(var + 1e-5f);
    }
    __syncthreads();
    float mean = stats[0], rstd = stats[1];
    #pragma unroll
    for (int q = 0; q < 2; ++q) {
        int j = tid + q * 256;
        float v = (r[q] - mean) * rstd * gamma[j] + beta[j];
        size_t o = (size_t)row * DM + j;
        if (isbf) ((bf16*)out)[o] = __float2bfloat16(v);
        else      ((float*)out)[o] = v;
    }
}

// ---------------------------------------------------------------------------
extern "C" void kernel_launch(void* const* d_in, const int* in_sizes, int n_in,
                              void* d_out, int out_size, void* d_ws, size_t ws_size,
                              hipStream_t stream)
{
    float* W = (float*)d_ws;
    float* ccw  = W;                       // 4096
    float* ccb  = ccw  + 4096;             // 1024
    float* cAlg = ccb  + 1024;             // 16
    float* cDsk = cAlg + 16;               // 1024
    float* cgam = cDsk + 1024;             // 512
    float* cbet = cgam + 512;              // 512
    float* bdtx = cbet + 512;              // 1152
    float* outp = bdtx + 1152;             // 4096x512 fp32
    bf16*  xbf  = (bf16*)(outp + 2097152); // 4096x512
    bf16*  xrb  = xbf  + 2097152;          // 4096x2048
    bf16*  xcb  = xrb  + 8388608;          // 4096x1024
    bf16*  ybf  = xcb  + 4194304;          // 4096x1024
    bf16*  dlx  = ybf  + 4194304;          // 4096x1152 (delta|B|C)
    bf16*  WtIn = dlx  + 4718592;          // 2048x512
    bf16*  WtDtx= WtIn + 1048576;          // 1152x1024
    bf16*  WtOut= WtDtx+ 1179648;          // 512x1024

    // 1) all prep (dtype detect per block, pack x, transposes, small params)
    prep_all<<<5057, 256, 0, stream>>>(
        d_in[0], d_in[1], d_in[5], d_in[4], d_in[9], d_in[2], d_in[3],
        d_in[7], d_in[8], d_in[10], d_in[11], d_in[6],
        xbf, WtIn, WtDtx, WtOut, ccw, ccb, cAlg, cDsk, cgam, cbet, bdtx);

    // 2) x_and_res = clip(x) @ W_in        [4096,2048] bf16, 1024 blocks
    gemm_mfma<64, 128, true><<<dim3(2048 / 128, ROWS / 64), 256, 0, stream>>>(
        xbf, WtIn, nullptr, xrb, ROWS, 2048, 512);

    // 3) depthwise causal conv + SiLU -> bf16 xc
    conv_silu<<<ROWS * DI / 256, 256, 0, stream>>>(xrb, ccw, ccb, xcb);

    // 4) [delta | ssm] = xc @ [W_dt | W_x] (+[b_dt|0])   [4096,1152] bf16
    gemm_mfma<64, 128, true><<<dim3(NDTX / 128, ROWS / 64), 256, 0, stream>>>(
        xcb, WtDtx, bdtx, dlx, ROWS, NDTX, DI);

    // 5) fused chunked selective scan -> gated bf16 y (one launch)
    scan_fused<<<256, 1024, 0, stream>>>(xcb, dlx, xrb, cAlg, cDsk, ybf);

    // 6) out_pre = y @ W_out               [4096,512] fp32, 512 blocks
    gemm_mfma<64, 64, false><<<dim3(DM / 64, ROWS / 64), 256, 0, stream>>>(
        ybf, WtOut, nullptr, outp, ROWS, DM, DI);

    // 7) LayerNorm(out_pre + clip(x)) -> out (dtype detected locally)
    ln_kernel<<<ROWS, 256, 0, stream>>>(outp, d_in[0], d_in[5], cgam, cbet, d_out);
}

// Round 8
// 217.975 us; speedup vs baseline: 5.8883x; 1.0385x over previous
//
#include <hip/hip_runtime.h>
#include <hip/hip_bf16.h>

typedef __hip_bfloat16 bf16;
typedef unsigned short ushort_t;
typedef unsigned int uint_t;
typedef __attribute__((ext_vector_type(8))) __bf16 bf16x8;
typedef __attribute__((ext_vector_type(8))) ushort_t u16x8;
typedef __attribute__((ext_vector_type(4))) float f32x4;

#define BB 4
#define LL 1024
#define DM 512
#define DS 16
#define DI 1024
#define ROWS 4096
#define NC 64
#define CT 16
#define NDTX 1152   // padded N for the fused [delta | ssm] GEMM (9*128)

__device__ __forceinline__ float b2f(bf16 v) { return __bfloat162float(v); }

__device__ __forceinline__ float load_flag(const void* src, int i, int isbf)
{
    return isbf ? b2f(((const bf16*)src)[i]) : ((const float*)src)[i];
}

__device__ __forceinline__ ushort_t f2b_bits(float v)
{
    bf16 t = __float2bfloat16(v);
    return *(ushort_t*)&t;
}

__device__ __forceinline__ float bits2f(ushort_t u)
{
    uint_t w = ((uint_t)u) << 16;
    return __uint_as_float(w);
}

// Per-block dtype detection: sample 256 16-bit words of W_dt (scale 0.02).
// bf16 data -> 0 words with bf16-exponent >= 127; fp32 data -> ~64 of 256.
__device__ __forceinline__ int detect_local(const ushort_t* wdt)
{
    __shared__ int bad;
    if (threadIdx.x == 0) bad = 0;
    __syncthreads();
    ushort_t u = wdt[threadIdx.x & 255];
    if (((u >> 7) & 0xFF) >= 127) atomicAdd(&bad, 1);
    __syncthreads();
    return (bad <= 8) ? 1 : 0;   // 1 = bf16 inputs
}

// ---------------------------------------------------------------------------
// ALL prep in one launch. Block ranges:
//   [0,2048):      pack_x  (x -> clipped bf16, 4 elems/thread)
//   [2048,4640):   weight transposes (LDS 32x32 tile)
//   [4640,5057):   small params + dtx bias + WtDtx pad-zero
// ---------------------------------------------------------------------------
__global__ __launch_bounds__(256)
void prep_all(const void* x, const void* Win, const void* Wdt, const void* Wx,
              const void* Wout, const void* cw, const void* cb, const void* Alog,
              const void* Dsk, const void* gam, const void* bet, const void* bdt,
              bf16* __restrict__ xbf, bf16* __restrict__ WtIn,
              bf16* __restrict__ WtDtx, bf16* __restrict__ WtOut,
              float* __restrict__ ccw, float* __restrict__ ccb,
              float* __restrict__ cAlg, float* __restrict__ cDsk,
              float* __restrict__ cgam, float* __restrict__ cbet,
              float* __restrict__ bdtx)
{
    const int isbf = detect_local((const ushort_t*)Wdt);
    int blk = blockIdx.x;

    if (blk < 2048) {
        int idx = blk * 256 + threadIdx.x;
        float v[4];
        if (isbf) {
            uint2 raw = ((const uint2*)x)[idx];
            v[0] = __uint_as_float(raw.x << 16);
            v[1] = __uint_as_float(raw.x & 0xFFFF0000u);
            v[2] = __uint_as_float(raw.y << 16);
            v[3] = __uint_as_float(raw.y & 0xFFFF0000u);
        } else {
            float4 raw = ((const float4*)x)[idx];
            v[0] = raw.x; v[1] = raw.y; v[2] = raw.z; v[3] = raw.w;
        }
        uint_t b0, b1;
        b0 = f2b_bits(fminf(fmaxf(v[0], -10.f), 10.f))
           | ((uint_t)f2b_bits(fminf(fmaxf(v[1], -10.f), 10.f)) << 16);
        b1 = f2b_bits(fminf(fmaxf(v[2], -10.f), 10.f))
           | ((uint_t)f2b_bits(fminf(fmaxf(v[3], -10.f), 10.f)) << 16);
        uint2 ow; ow.x = b0; ow.y = b1;
        ((uint2*)xbf)[idx] = ow;
    } else if (blk < 4640) {
        int tb = blk - 2048;
        const void* src; bf16* dst; int K, Nsrc, tpr;
        if (tb < 1024)      { src = Win;  dst = WtIn;               K = 512;  Nsrc = 2048; tpr = 64; }
        else if (tb < 2048) { tb -= 1024; src = Wdt;  dst = WtDtx;  K = 1024; Nsrc = 1024; tpr = 32; }
        else if (tb < 2080) { tb -= 2048; src = Wx;   dst = WtDtx + 1024 * 1024; K = 1024; Nsrc = 32; tpr = 1; }
        else                { tb -= 2080; src = Wout; dst = WtOut;  K = 1024; Nsrc = 512;  tpr = 16; }
        int k0 = (tb / tpr) * 32, n0 = (tb % tpr) * 32;

        __shared__ float tile[32][33];
        int tx = threadIdx.x & 31, ty = threadIdx.x >> 5;
        #pragma unroll
        for (int j = 0; j < 4; ++j)
            tile[ty + 8 * j][tx] = load_flag(src, (k0 + ty + 8 * j) * Nsrc + n0 + tx, isbf);
        __syncthreads();
        #pragma unroll
        for (int j = 0; j < 4; ++j)
            dst[(size_t)(n0 + ty + 8 * j) * K + k0 + tx] = __float2bfloat16(tile[tx][ty + 8 * j]);
    } else {
        int i = (blk - 4640) * 256 + threadIdx.x;
        if (i < 4096)        ccw[i] = load_flag(cw, i, isbf);
        else if (i < 5120)   ccb[i - 4096] = load_flag(cb, i - 4096, isbf);
        else if (i < 5136)   cAlg[i - 5120] = load_flag(Alog, i - 5120, isbf);
        else if (i < 6160)   cDsk[i - 5136] = load_flag(Dsk, i - 5136, isbf);
        else if (i < 6672)   cgam[i - 6160] = load_flag(gam, i - 6160, isbf);
        else if (i < 7184)   cbet[i - 6672] = load_flag(bet, i - 6672, isbf);
        else if (i < 8336) {
            int j = i - 7184;
            bdtx[j] = (j < DI) ? load_flag(bdt, j, isbf) : 0.f;
        } else if (i < 106640) {
            (WtDtx + 1056 * 1024)[i - 8336] = __float2bfloat16(0.f);
        }
    }
}

// ---------------------------------------------------------------------------
// MFMA bf16 GEMM: C[M][N] = A[M][K] * Bt[N][K]^T (+bias).
// TM x TN tile, 4 waves (2x2), 16x16x32 frags, BK=64 (two 32-k halves per
// staging barrier), global_load_lds width-16 with XOR 8-chunk swizzle.
// ---------------------------------------------------------------------------
__device__ __forceinline__ void gload16(const bf16* g, ushort_t* l)
{
    __builtin_amdgcn_global_load_lds(
        (const __attribute__((address_space(1))) void*)g,
        (__attribute__((address_space(3))) void*)l, 16, 0, 0);
}

template <int TM, int TN, bool OBF>
__global__ __launch_bounds__(256)
void gemm_mfma(const bf16* __restrict__ A, const bf16* __restrict__ Bt,
               const float* __restrict__ bias, void* __restrict__ Cv,
               int M, int N, int K)
{
    constexpr int MI = TM / 32, NJ = TN / 32;
    constexpr int NQA = TM * 8 / 256;
    constexpr int NQB = TN * 8 / 256;
    __shared__ ushort_t As[TM * 64];
    __shared__ ushort_t Bs[TN * 64];

    const int tid = threadIdx.x;
    const int lane = tid & 63;
    const int w = tid >> 6;
    const int wr = w >> 1, wc = w & 1;
    const int m0 = blockIdx.y * TM;
    const int n0 = blockIdx.x * TN;

    const bf16* gA[NQA]; ushort_t* lA[NQA];
    #pragma unroll
    for (int q = 0; q < NQA; ++q) {
        int p = q * 256 + tid;
        int row = p >> 3, kc = ((p & 7) - row) & 7;
        gA[q] = A + (size_t)(m0 + row) * K + kc * 8;
        lA[q] = &As[(q * 256 + w * 64) * 8];
    }
    const bf16* gB[NQB]; ushort_t* lB[NQB];
    #pragma unroll
    for (int q = 0; q < NQB; ++q) {
        int p = q * 256 + tid;
        int row = p >> 3, kc = ((p & 7) - row) & 7;
        gB[q] = Bt + (size_t)(n0 + row) * K + kc * 8;
        lB[q] = &Bs[(q * 256 + w * 64) * 8];
    }

    f32x4 acc[MI][NJ];
    #pragma unroll
    for (int i = 0; i < MI; ++i)
        #pragma unroll
        for (int j = 0; j < NJ; ++j)
            acc[i][j] = (f32x4){0.f, 0.f, 0.f, 0.f};

    const int ko = lane >> 4;
    const int ml = lane & 15;

    for (int k0 = 0; k0 < K; k0 += 64) {
        #pragma unroll
        for (int q = 0; q < NQA; ++q) gload16(gA[q] + k0, lA[q]);
        #pragma unroll
        for (int q = 0; q < NQB; ++q) gload16(gB[q] + k0, lB[q]);
        __syncthreads();

        #pragma unroll
        for (int half = 0; half < 2; ++half) {
            bf16x8 af[MI], bfr[NJ];
            #pragma unroll
            for (int i = 0; i < MI; ++i) {
                int m = wr * (TM / 2) + i * 16 + ml;
                af[i] = *(const bf16x8*)&As[(m * 8 + ((half * 4 + ko + m) & 7)) * 8];
            }
            #pragma unroll
            for (int j = 0; j < NJ; ++j) {
                int n = wc * (TN / 2) + j * 16 + ml;
                bfr[j] = *(const bf16x8*)&Bs[(n * 8 + ((half * 4 + ko + n) & 7)) * 8];
            }
            #pragma unroll
            for (int i = 0; i < MI; ++i)
                #pragma unroll
                for (int j = 0; j < NJ; ++j)
                    acc[i][j] = __builtin_amdgcn_mfma_f32_16x16x32_bf16(
                        af[i], bfr[j], acc[i][j], 0, 0, 0);
        }
        __syncthreads();
    }

    const int rq = lane >> 4;
    #pragma unroll
    for (int j = 0; j < NJ; ++j) {
        int n = n0 + wc * (TN / 2) + j * 16 + ml;
        float bv = bias ? bias[n] : 0.f;
        #pragma unroll
        for (int i = 0; i < MI; ++i) {
            int mb = m0 + wr * (TM / 2) + i * 16 + rq * 4;
            #pragma unroll
            for (int r = 0; r < 4; ++r) {
                float v = acc[i][j][r] + bv;
                if (OBF) ((bf16*)Cv)[(size_t)(mb + r) * N + n] = __float2bfloat16(v);
                else     ((float*)Cv)[(size_t)(mb + r) * N + n] = v;
            }
        }
    }
}

// ---------------------------------------------------------------------------
// Depthwise causal conv (width 4) + SiLU, 8 channels/thread, 16B vector IO.
// ---------------------------------------------------------------------------
__global__ __launch_bounds__(256)
void conv_silu(const bf16* __restrict__ xrb, const float* __restrict__ cw,
               const float* __restrict__ cb, bf16* __restrict__ xcb)
{
    int idx = blockIdx.x * 256 + threadIdx.x;      // ROWS*DI/8 threads
    int i = (idx & 127) * 8;                       // channel base
    int row = idx >> 7;
    int t = row & (LL - 1);

    const u16x8 zv = {0, 0, 0, 0, 0, 0, 0, 0};
    const ushort_t* base = (const ushort_t*)(xrb) + (size_t)row * 2048 + i;
    u16x8 r3 = *(const u16x8*)base;
    u16x8 r2 = (t >= 1) ? *(const u16x8*)(base - 2048) : zv;
    u16x8 r1 = (t >= 2) ? *(const u16x8*)(base - 4096) : zv;
    u16x8 r0 = (t >= 3) ? *(const u16x8*)(base - 6144) : zv;

    u16x8 out;
    #pragma unroll
    for (int k = 0; k < 8; ++k) {
        float4 w = ((const float4*)cw)[i + k];     // cw[(i+k)*4 .. +3]
        float acc = cb[i + k];
        acc = fmaf(bits2f(r0[k]), w.x, acc);
        acc = fmaf(bits2f(r1[k]), w.y, acc);
        acc = fmaf(bits2f(r2[k]), w.z, acc);
        acc = fmaf(bits2f(r3[k]), w.w, acc);
        out[k] = f2b_bits(acc / (1.f + __expf(-acc)));
    }
    *(u16x8*)((ushort_t*)xcb + (size_t)row * DI + i) = out;
}

// ---------------------------------------------------------------------------
// FUSED chunked selective scan, no per-thread arrays (no scratch spill).
// Grid: 256 blocks = 4 batches x 64 channel-groups; block = 16 ch x 64 chunks.
// LDS: one uint per (s,c,chl) packing (P=prod dA, Q=h_end) as bf16 pair,
// laid out [s][c][chl] -> lane-consecutive 4B = conflict-free.
// Pass C re-reads d,u from L2 instead of caching in (spilled) arrays.
// ---------------------------------------------------------------------------
__global__ __launch_bounds__(1024)
void scan_fused(const bf16* __restrict__ xcb, const bf16* __restrict__ dlx,
                const bf16* __restrict__ xrb, const float* __restrict__ A_log,
                const float* __restrict__ Dskip, bf16* __restrict__ ybf)
{
    __shared__ uint_t lsum[DS * NC * 16];   // 64 KB

    const int tid = threadIdx.x;
    const int b = blockIdx.x >> 6;
    const int ch0 = (blockIdx.x & 63) << 4;
    const int chl = tid & 15;
    const int c = tid >> 4;                  // chunk 0..63
    const int i = ch0 + chl;

    float a[DS];
    #pragma unroll
    for (int s = 0; s < DS; ++s) a[s] = A_log[s];

    const int row0 = b * LL + c * CT;
    float h[DS] = {};
    float p[DS];
    #pragma unroll
    for (int s = 0; s < DS; ++s) p[s] = 1.f;

    // ---- Pass A: chunk recurrence from h=0
    for (int t = 0; t < CT; ++t) {
        const size_t row = row0 + t;
        float d = bits2f(((const ushort_t*)dlx)[row * NDTX + i]);
        float u = bits2f(((const ushort_t*)xcb)[row * DI + i]);
        float du = d * u;
        const u16x8* sp = (const u16x8*)(dlx + row * NDTX + 1024);
        u16x8 B0 = sp[0], B1 = sp[1];
        #pragma unroll
        for (int s = 0; s < DS; ++s) {
            float e = fminf(fmaxf(d * a[s], -5.f), 5.f);
            float dA = __expf(e);
            float Bv = bits2f(s < 8 ? B0[s] : B1[s - 8]);
            h[s] = fmaf(dA, h[s], du * Bv);
            p[s] *= dA;
        }
    }
    #pragma unroll
    for (int s = 0; s < DS; ++s)
        lsum[s * 1024 + tid] = (uint_t)f2b_bits(p[s]) | ((uint_t)f2b_bits(h[s]) << 16);
    __syncthreads();

    // ---- Combine (threads 0..255): (chl,s) serial over 64 chunks
    if (tid < 256) {
        int cl = tid & 15, s = tid >> 4;
        float hh = 0.f;
        for (int cc = 0; cc < NC; ++cc) {
            int off = s * 1024 + cc * 16 + cl;
            uint_t wrd = lsum[off];
            float pp = bits2f((ushort_t)(wrd & 0xFFFF));
            float qq = bits2f((ushort_t)(wrd >> 16));
            lsum[off] = (uint_t)f2b_bits(hh);      // h at chunk start
            hh = fmaf(pp, hh, qq);
        }
    }
    __syncthreads();

    #pragma unroll
    for (int s = 0; s < DS; ++s) h[s] = bits2f((ushort_t)lsum[s * 1024 + tid]);

    const float dsk = Dskip[i];
    // ---- Pass C: rerun from true h_start, emit gated y
    for (int t = 0; t < CT; ++t) {
        const size_t row = row0 + t;
        float d = bits2f(((const ushort_t*)dlx)[row * NDTX + i]);
        float u = bits2f(((const ushort_t*)xcb)[row * DI + i]);
        float du = d * u;
        const u16x8* sp = (const u16x8*)(dlx + row * NDTX + 1024);
        u16x8 B0 = sp[0], B1 = sp[1], C0 = sp[2], C1 = sp[3];
        float y = 0.f;
        #pragma unroll
        for (int s = 0; s < DS; ++s) {
            float e = fminf(fmaxf(d * a[s], -5.f), 5.f);
            float dA = __expf(e);
            float Bv = bits2f(s < 8 ? B0[s] : B1[s - 8]);
            float Cv = bits2f(s < 8 ? C0[s] : C1[s - 8]);
            h[s] = fmaf(dA, h[s], du * Bv);
            y = fmaf(h[s], Cv, y);
        }
        float res = bits2f(((const ushort_t*)xrb)[row * 2048 + DI + i]);
        float g = res / (1.f + __expf(-res));
        ybf[row * DI + i] = __float2bfloat16((y + u * dsk) * g);
    }
}

// ---------------------------------------------------------------------------
// r = outp + clip(x_raw); LayerNorm over 512; dtype detected locally.
// ---------------------------------------------------------------------------
__global__ __launch_bounds__(256)
void ln_kernel(const float* __restrict__ outp, const void* __restrict__ xsrc,
               const void* __restrict__ wdt_probe,
               const float* __restrict__ gamma, const float* __restrict__ beta,
               void* __restrict__ out)
{
    const int isbf = detect_local((const ushort_t*)wdt_probe);
    const int row = blockIdx.x;
    const int tid = threadIdx.x;

    float r[2];
    float sum = 0.f, ss = 0.f;
    #pragma unroll
    for (int q = 0; q < 2; ++q) {
        int j = tid + q * 256;
        float xv = load_flag(xsrc, row * DM + j, isbf);
        xv = fminf(fmaxf(xv, -10.f), 10.f);
        float v = outp[(size_t)row * DM + j] + xv;
        r[q] = v;
        sum += v;
        ss = fmaf(v, v, ss);
    }
    #pragma unroll
    for (int off = 32; off >= 1; off >>= 1) {
        sum += __shfl_down(sum, off);
        ss  += __shfl_down(ss, off);
    }
    __shared__ float s1[4], s2[4];
    __shared__ float stats[2];
    int wid = tid >> 6, lane = tid & 63;
    if (lane == 0) { s1[wid] = sum; s2[wid] = ss; }
    __syncthreads();
    if (tid == 0) {
        float S = s1[0] + s1[1] + s1[2] + s1[3];
        float Qq = s2[0] + s2[1] + s2[2] + s2[3];
        float mean = S / DM;
        float var = Qq / DM - mean * mean;
        stats[0] = mean;
        stats[1] = rsqrtf(var + 1e-5f);
    }
    __syncthreads();
    float mean = stats[0], rstd = stats[1];
    #pragma unroll
    for (int q = 0; q < 2; ++q) {
        int j = tid + q * 256;
        float v = (r[q] - mean) * rstd * gamma[j] + beta[j];
        size_t o = (size_t)row * DM + j;
        if (isbf) ((bf16*)out)[o] = __float2bfloat16(v);
        else      ((float*)out)[o] = v;
    }
}

// ---------------------------------------------------------------------------
extern "C" void kernel_launch(void* const* d_in, const int* in_sizes, int n_in,
                              void* d_out, int out_size, void* d_ws, size_t ws_size,
                              hipStream_t stream)
{
    float* W = (float*)d_ws;
    float* ccw  = W;                       // 4096
    float* ccb  = ccw  + 4096;             // 1024
    float* cAlg = ccb  + 1024;             // 16
    float* cDsk = cAlg + 16;               // 1024
    float* cgam = cDsk + 1024;             // 512
    float* cbet = cgam + 512;              // 512
    float* bdtx = cbet + 512;              // 1152
    float* outp = bdtx + 1152;             // 4096x512 fp32
    bf16*  xbf  = (bf16*)(outp + 2097152); // 4096x512
    bf16*  xrb  = xbf  + 2097152;          // 4096x2048
    bf16*  xcb  = xrb  + 8388608;          // 4096x1024
    bf16*  ybf  = xcb  + 4194304;          // 4096x1024
    bf16*  dlx  = ybf  + 4194304;          // 4096x1152 (delta|B|C)
    bf16*  WtIn = dlx  + 4718592;          // 2048x512
    bf16*  WtDtx= WtIn + 1048576;          // 1152x1024
    bf16*  WtOut= WtDtx+ 1179648;          // 512x1024

    // 1) all prep (dtype detect per block, pack x, transposes, small params)
    prep_all<<<5057, 256, 0, stream>>>(
        d_in[0], d_in[1], d_in[5], d_in[4], d_in[9], d_in[2], d_in[3],
        d_in[7], d_in[8], d_in[10], d_in[11], d_in[6],
        xbf, WtIn, WtDtx, WtOut, ccw, ccb, cAlg, cDsk, cgam, cbet, bdtx);

    // 2) x_and_res = clip(x) @ W_in        [4096,2048] bf16, 1024 blocks
    gemm_mfma<64, 128, true><<<dim3(2048 / 128, ROWS / 64), 256, 0, stream>>>(
        xbf, WtIn, nullptr, xrb, ROWS, 2048, 512);

    // 3) depthwise causal conv + SiLU -> bf16 xc (8 ch/thread)
    conv_silu<<<ROWS * DI / 8 / 256, 256, 0, stream>>>(xrb, ccw, ccb, xcb);

    // 4) [delta | ssm] = xc @ [W_dt | W_x] (+[b_dt|0])   [4096,1152] bf16
    gemm_mfma<64, 128, true><<<dim3(NDTX / 128, ROWS / 64), 256, 0, stream>>>(
        xcb, WtDtx, bdtx, dlx, ROWS, NDTX, DI);

    // 5) fused chunked selective scan -> gated bf16 y (one launch)
    scan_fused<<<256, 1024, 0, stream>>>(xcb, dlx, xrb, cAlg, cDsk, ybf);

    // 6) out_pre = y @ W_out               [4096,512] fp32, 512 blocks
    gemm_mfma<64, 64, false><<<dim3(DM / 64, ROWS / 64), 256, 0, stream>>>(
        ybf, WtOut, nullptr, outp, ROWS, DM, DI);

    // 7) LayerNorm(out_pre + clip(x)) -> out (dtype detected locally)
    ln_kernel<<<ROWS, 256, 0, stream>>>(outp, d_in[0], d_in[5], cgam, cbet, d_out);
}